// Round 8
// baseline (916.617 us; speedup 1.0000x reference)
//
#include <hip/hip_runtime.h>

#define NN 20000
#define NE 640000
#define NTILES (NE / 64)
#define XSTR 72    // x_lds / a_lds row stride (shorts): 16B-aligned rows
#define HSTR 136   // h_lds row stride (shorts), cols XOR-swizzled by (m&8)

typedef float f32x4 __attribute__((ext_vector_type(4)));
typedef short short8 __attribute__((ext_vector_type(8)));
union S8I4 { int4 i; short8 s; };

#define MFMA(a, b, c) __builtin_amdgcn_mfma_f32_16x16x32_bf16((a), (b), (c), 0, 0, 0)

__device__ __forceinline__ short f2bf(float f) {
    unsigned u = __float_as_uint(f);
    u = (u + 0x7FFFu + ((u >> 16) & 1u)) >> 16;   // RNE
    return (short)u;
}
__device__ __forceinline__ float bf2f(short s) {
    return __uint_as_float(((unsigned)(unsigned short)s) << 16);
}

// ---------------- fused prologue: prep_w + node_enc + degree ----------------
__global__ __launch_bounds__(256) void k_pre(
    const float* __restrict__ x, const int* __restrict__ eidx,
    const float* __restrict__ enc_w, const float* __restrict__ enc_b,
    const float* __restrict__ enc_g, const float* __restrict__ enc_bb,
    const float* __restrict__ w1a, const float* __restrict__ w2a,
    const float* __restrict__ w1b, const float* __restrict__ w2b,
    const float* __restrict__ eencw,
    const float* __restrict__ g0, const float* __restrict__ be0,
    const float* __restrict__ g1, const float* __restrict__ be1,
    const float* __restrict__ b1a, const float* __restrict__ b1b,
    float* __restrict__ xenc, short* __restrict__ xb, int* __restrict__ deg,
    short* __restrict__ p1a, short* __restrict__ p2a,
    short* __restrict__ p1b, short* __restrict__ p2b,
    short* __restrict__ pbenc, float* __restrict__ b1ea, float* __restrict__ b1eb)
{
    const int bid = blockIdx.x, tid = threadIdx.x;
    // ---- node encoder ----
    {
        int node = bid * 4 + (tid >> 6);
        int lane = tid & 63;
        if (node < NN) {
            const float* xr = x + (size_t)node * 96;
            float acc = enc_b[lane];
            #pragma unroll
            for (int k = 0; k < 96; ++k) acc = fmaf(xr[k], enc_w[k * 64 + lane], acc);
            float s = acc, s2 = acc * acc;
            #pragma unroll
            for (int off = 32; off; off >>= 1) { s += __shfl_xor(s, off); s2 += __shfl_xor(s2, off); }
            float mu = s * 0.015625f, var = s2 * 0.015625f - mu * mu;
            float r = rsqrtf(var + 1e-5f);
            float v = (acc - mu) * r * enc_g[lane] + enc_bb[lane];
            size_t idx = (size_t)node * 64 + lane;
            xenc[idx] = v;
            xb[idx] = f2bf(v);
        }
    }
    // ---- degree ----
    if (bid < 2500) {
        int e = bid * 256 + tid;
        atomicAdd(&deg[eidx[NE + e]], 1);
    }
    // ---- weight pre-pack ----
    if (bid < 96) {
        int idx = bid * 256 + tid;
        {
            int f = idx >> 9, l = (idx >> 3) & 63, j = idx & 7;
            int kt = f >> 3, nt = f & 7;
            int k = kt * 32 + ((l >> 4) << 3) + j;
            int n = (nt << 4) + (l & 15);
            float sa = (k >= 128) ? g0[k - 128] : 1.f;
            float sb = (k >= 128) ? g1[k - 128] : 1.f;
            p1a[idx] = f2bf(sa * w1a[k * 128 + n]);
            p1b[idx] = f2bf(sb * w1b[k * 128 + n]);
        }
        if (idx < 8192) {
            int f = idx >> 9, l = (idx >> 3) & 63, j = idx & 7;
            int kt = f >> 2, nt = f & 3;
            int k = kt * 32 + ((l >> 4) << 3) + j;
            int n = (nt << 4) + (l & 15);
            p2a[idx] = f2bf(w2a[k * 64 + n]);
            p2b[idx] = f2bf(w2b[k * 64 + n]);
        }
        if (idx < 2048) {   // encoder B: K padded 16->32
            int f = idx >> 9, l = (idx >> 3) & 63, j = idx & 7;
            int k = ((l >> 4) << 3) + j;
            int n = (f << 4) + (l & 15);
            pbenc[idx] = (k < 16) ? f2bf(eencw[k * 64 + n]) : (short)0;
        }
        if (idx < 256) {
            int conv = idx >> 7, j = idx & 127;
            const float* w1  = conv ? w1b : w1a;
            const float* bet = conv ? be1 : be0;
            float s = conv ? b1b[j] : b1a[j];
            for (int k = 0; k < 64; ++k) s = fmaf(bet[k], w1[(128 + k) * 128 + j], s);
            (conv ? b1eb : b1ea)[j] = s;
        }
    }
}

__global__ __launch_bounds__(1024) void k_scan(
    const int* __restrict__ deg, int* __restrict__ row_ptr, int* __restrict__ cursor)
{
    __shared__ int sums[1024];
    const int T = 1024, CHUNK = (NN + 1023) / 1024;
    int tid = threadIdx.x;
    int base = tid * CHUNK;
    int local = 0;
    for (int i = 0; i < CHUNK; ++i) { int idx = base + i; if (idx < NN) local += deg[idx]; }
    sums[tid] = local;
    __syncthreads();
    for (int off = 1; off < T; off <<= 1) {
        int v = (tid >= off) ? sums[tid - off] : 0;
        __syncthreads();
        sums[tid] += v;
        __syncthreads();
    }
    int run = (tid == 0) ? 0 : sums[tid - 1];
    for (int i = 0; i < CHUNK; ++i) {
        int idx = base + i;
        if (idx < NN) { row_ptr[idx] = run; cursor[idx] = run; run += deg[idx]; }
    }
    if (tid == T - 1) row_ptr[NN] = run;
}

__global__ __launch_bounds__(256) void k_scatter(
    const int* __restrict__ eidx, int* __restrict__ cursor,
    int* __restrict__ psrc, int* __restrict__ pdst, int* __restrict__ peid)
{
    int e = blockIdx.x * 256 + threadIdx.x;
    if (e < NE) {
        int s = eidx[e], d = eidx[NE + e];
        int p = atomicAdd(&cursor[d], 1);
        psrc[p] = s; pdst[p] = d; peid[p] = e;
    }
}

// ---------------- MFMA edge conv ----------------
// LDS overlay: h_lds reuses x_lds region (dead after layer1) -> 28 KB/block.
// LN: per-row (sum,sumsq) only; normalization applied reader-side in layer1.
template <int MODE>
__global__ __launch_bounds__(256, 4) void k_conv_mfma(
    const short* __restrict__ xb,
    const int* __restrict__ psrc, const int* __restrict__ pdst,
    const int* __restrict__ peid,                      // MODE0
    const float* __restrict__ eattr,                   // MODE0
    const short* __restrict__ pbenc,                   // MODE0
    const float* __restrict__ encb,                    // MODE0 (eenc_b)
    const short* __restrict__ w1p, const float* __restrict__ b1e,
    const short* __restrict__ w2p, const float* __restrict__ b2,
    short* __restrict__ msgb)
{
    __shared__ short smem[192 * XSTR];     // x: rows 0..127; a: rows 128..191
    __shared__ float2 stats[64];
    short* x_lds = smem;
    short* a_lds = smem + 128 * XSTR;
    short* h_lds = smem;                   // overlay on x region (64*HSTR <= 128*XSTR)
    const int tid  = threadIdx.x;
    const int wave = tid >> 6;
    const int lane = tid & 63;
    const int quad = lane >> 4;
    const int l15  = lane & 15;
    const int qoff = quad * 8;

    short8 B1[6][2], B2[4], Benc;
    {
        const int4* p = (const int4*)w1p;
        #pragma unroll
        for (int kt = 0; kt < 6; ++kt)
            #pragma unroll
            for (int nf = 0; nf < 2; ++nf) {
                S8I4 u; u.i = p[(kt * 8 + wave * 2 + nf) * 64 + lane];
                B1[kt][nf] = u.s;
            }
        const int4* q = (const int4*)w2p;
        #pragma unroll
        for (int kt = 0; kt < 4; ++kt) { S8I4 u; u.i = q[(kt * 4 + wave) * 64 + lane]; B2[kt] = u.s; }
        if (MODE == 0) { S8I4 u; u.i = ((const int4*)pbenc)[wave * 64 + lane]; Benc = u.s; }
    }
    const float b1v0 = b1e[wave * 32 + l15];
    const float b1v1 = b1e[wave * 32 + 16 + l15];
    const float b2v  = b2[wave * 16 + l15];
    const float encbv = (MODE == 0) ? encb[wave * 16 + l15] : 0.f;

    for (int t = blockIdx.x; t < NTILES; t += gridDim.x) {
        const int ebase = t * 64;
        __syncthreads();   // prev tile's layer2 (h in x region) done before restage

        // ---- stage x_dst (rows 0..63) and x_src (rows 64..127) ----
        #pragma unroll
        for (int it = 0; it < 4; ++it) {
            int item = it * 256 + tid;            // 0..1023
            int row = item >> 3, c = item & 7;
            int slot = ebase + (row & 63);
            int node = (row < 64) ? pdst[slot] : psrc[slot];
            *(int4*)(x_lds + row * XSTR + c * 8) =
                *(const int4*)(xb + (size_t)node * 64 + c * 8);
        }
        // ---- stage ea source into a_lds ----
        if (MODE == 1) {
            // stats folded into staging: 8 consecutive lanes share a row
            #pragma unroll
            for (int it = 0; it < 2; ++it) {
                int item = it * 256 + tid;        // 0..511
                int row = item >> 3, c = item & 7;
                S8I4 u;
                u.i = *(const int4*)(msgb + (size_t)(ebase + row) * 64 + c * 8);
                *(int4*)(a_lds + row * XSTR + c * 8) = u.i;
                float s = 0.f, s2 = 0.f;
                #pragma unroll
                for (int j = 0; j < 8; ++j) {
                    float v = bf2f(u.s[j]);
                    s += v; s2 = fmaf(v, v, s2);
                }
                s  += __shfl_xor(s, 1);  s  += __shfl_xor(s, 2);  s  += __shfl_xor(s, 4);
                s2 += __shfl_xor(s2, 1); s2 += __shfl_xor(s2, 2); s2 += __shfl_xor(s2, 4);
                if ((tid & 7) == 0) stats[row] = make_float2(s, s2);
            }
        } else {
            // fused edge encoder (K-padded MFMA from raw attrs)
            #pragma unroll
            for (int mt = 0; mt < 4; ++mt) {
                int slot = ebase + mt * 16 + l15;
                short8 ae = {0, 0, 0, 0, 0, 0, 0, 0};
                if (quad < 2) {
                    int row = peid[slot];
                    const float* ap = eattr + (size_t)row * 16 + qoff;
                    float4 u0 = *(const float4*)ap;
                    float4 u1 = *(const float4*)(ap + 4);
                    ae[0] = f2bf(u0.x); ae[1] = f2bf(u0.y); ae[2] = f2bf(u0.z); ae[3] = f2bf(u0.w);
                    ae[4] = f2bf(u1.x); ae[5] = f2bf(u1.y); ae[6] = f2bf(u1.z); ae[7] = f2bf(u1.w);
                }
                f32x4 ac = {encbv, encbv, encbv, encbv};
                ac = MFMA(ae, Benc, ac);
                #pragma unroll
                for (int r = 0; r < 4; ++r)
                    a_lds[(mt * 16 + quad * 4 + r) * XSTR + wave * 16 + l15] = f2bf(ac[r]);
            }
        }
        __syncthreads();

        if (MODE == 0) {
            // read-only stats pass: 4 consecutive lanes per row
            int m = tid >> 2, q = tid & 3;
            const short* rp = a_lds + m * XSTR + q * 16;
            S8I4 u0, u1;
            u0.i = *(const int4*)rp;
            u1.i = *(const int4*)(rp + 8);
            float s = 0.f, s2 = 0.f;
            #pragma unroll
            for (int j = 0; j < 8; ++j) {
                float v0 = bf2f(u0.s[j]), v1 = bf2f(u1.s[j]);
                s += v0 + v1;
                s2 = fmaf(v0, v0, fmaf(v1, v1, s2));
            }
            s  += __shfl_xor(s, 1);  s  += __shfl_xor(s, 2);
            s2 += __shfl_xor(s2, 1); s2 += __shfl_xor(s2, 2);
            if (q == 0) stats[m] = make_float2(s, s2);
            __syncthreads();
        }

        // ---- layer 1 (reader-side LN on ea fragments) ----
        f32x4 acc[4][2];
        #pragma unroll
        for (int mt = 0; mt < 4; ++mt) {
            acc[mt][0] = (f32x4){b1v0, b1v0, b1v0, b1v0};
            acc[mt][1] = (f32x4){b1v1, b1v1, b1v1, b1v1};
        }
        #pragma unroll
        for (int mt = 0; mt < 4; ++mt) {
            const short* xr = x_lds + (mt * 16 + l15) * XSTR;
            const short* sr = xr + 64 * XSTR;
            const short* ar = a_lds + (mt * 16 + l15) * XSTR;
            float2 sv = stats[mt * 16 + l15];
            float mu = sv.x * 0.015625f, var = sv.y * 0.015625f - mu * mu;
            float rs = rsqrtf(var + 1e-5f);
            float nb = -mu * rs;
            S8I4 a0, a1, a2, a3, r4, r5;
            a0.i = *(const int4*)(xr + qoff);
            a1.i = *(const int4*)(xr + 32 + qoff);
            a2.i = *(const int4*)(sr + qoff);
            a3.i = *(const int4*)(sr + 32 + qoff);
            r4.i = *(const int4*)(ar + qoff);
            r5.i = *(const int4*)(ar + 32 + qoff);
            short8 a4, a5;
            #pragma unroll
            for (int j = 0; j < 8; ++j) {
                a4[j] = f2bf(fmaf(bf2f(r4.s[j]), rs, nb));
                a5[j] = f2bf(fmaf(bf2f(r5.s[j]), rs, nb));
            }
            acc[mt][0] = MFMA(a0.s, B1[0][0], acc[mt][0]);
            acc[mt][1] = MFMA(a0.s, B1[0][1], acc[mt][1]);
            acc[mt][0] = MFMA(a1.s, B1[1][0], acc[mt][0]);
            acc[mt][1] = MFMA(a1.s, B1[1][1], acc[mt][1]);
            acc[mt][0] = MFMA(a2.s, B1[2][0], acc[mt][0]);
            acc[mt][1] = MFMA(a2.s, B1[2][1], acc[mt][1]);
            acc[mt][0] = MFMA(a3.s, B1[3][0], acc[mt][0]);
            acc[mt][1] = MFMA(a3.s, B1[3][1], acc[mt][1]);
            acc[mt][0] = MFMA(a4, B1[4][0], acc[mt][0]);
            acc[mt][1] = MFMA(a4, B1[4][1], acc[mt][1]);
            acc[mt][0] = MFMA(a5, B1[5][0], acc[mt][0]);
            acc[mt][1] = MFMA(a5, B1[5][1], acc[mt][1]);
        }
        __syncthreads();   // all x/a reads done before h overwrites x region

        // ---- relu -> h_lds (overlaid on x region) ----
        #pragma unroll
        for (int mt = 0; mt < 4; ++mt)
            #pragma unroll
            for (int nf = 0; nf < 2; ++nf) {
                int n = wave * 32 + nf * 16 + l15;
                #pragma unroll
                for (int r = 0; r < 4; ++r) {
                    int m = mt * 16 + quad * 4 + r;
                    h_lds[m * HSTR + (n ^ (m & 8))] = f2bf(fmaxf(acc[mt][nf][r], 0.f));
                }
            }
        __syncthreads();

        // ---- layer 2 ----
        f32x4 acc2[4];
        #pragma unroll
        for (int mt = 0; mt < 4; ++mt) acc2[mt] = (f32x4){b2v, b2v, b2v, b2v};
        #pragma unroll
        for (int mt = 0; mt < 4; ++mt) {
            int m = mt * 16 + l15;
            const short* hr = h_lds + m * HSTR;
            int sw = m & 8;
            #pragma unroll
            for (int kt = 0; kt < 4; ++kt) {
                S8I4 u; u.i = *(const int4*)(hr + ((kt * 32 + qoff) ^ sw));
                acc2[mt] = MFMA(u.s, B2[kt], acc2[mt]);
            }
        }
        #pragma unroll
        for (int mt = 0; mt < 4; ++mt) {
            int n = wave * 16 + l15;
            #pragma unroll
            for (int r = 0; r < 4; ++r) {
                int m = mt * 16 + quad * 4 + r;
                msgb[(size_t)(ebase + m) * 64 + n] = f2bf(acc2[mt][r]);
            }
        }
    }
}

// ---------------- gathers: 4 edges in flight, shuffle-only redistribute ------
// lane = (gq = lane>>4: edge phase 0..3, cl = lane&15: channel group 0..15).
// After xor16/32 butterfly every lane holds full sums for channels 4cl..4cl+3;
// lane L fetches its channel L via __shfl from lane L>>2 (no LDS, no barriers).
__device__ __forceinline__ float gather_agg(
    const short* __restrict__ msgb, int beg, int end, float t, int lane)
{
    const int cl = lane & 15, gq = lane >> 4;
    float den0 = 0.f, den1 = 0.f, den2 = 0.f, den3 = 0.f;
    float num0 = 0.f, num1 = 0.f, num2 = 0.f, num3 = 0.f;
    for (int i = beg + gq; i < end; i += 4) {
        int2 u = *(const int2*)(msgb + (size_t)i * 64 + cl * 4);
        float m0 = bf2f((short)(u.x & 0xffff));
        float m1 = bf2f((short)(u.x >> 16));
        float m2 = bf2f((short)(u.y & 0xffff));
        float m3 = bf2f((short)(u.y >> 16));
        float e0 = __expf(m0 * t), e1 = __expf(m1 * t);
        float e2 = __expf(m2 * t), e3 = __expf(m3 * t);
        den0 += e0; num0 = fmaf(m0, e0, num0);
        den1 += e1; num1 = fmaf(m1, e1, num1);
        den2 += e2; num2 = fmaf(m2, e2, num2);
        den3 += e3; num3 = fmaf(m3, e3, num3);
    }
    den0 += __shfl_xor(den0, 16); den0 += __shfl_xor(den0, 32);
    den1 += __shfl_xor(den1, 16); den1 += __shfl_xor(den1, 32);
    den2 += __shfl_xor(den2, 16); den2 += __shfl_xor(den2, 32);
    den3 += __shfl_xor(den3, 16); den3 += __shfl_xor(den3, 32);
    num0 += __shfl_xor(num0, 16); num0 += __shfl_xor(num0, 32);
    num1 += __shfl_xor(num1, 16); num1 += __shfl_xor(num1, 32);
    num2 += __shfl_xor(num2, 16); num2 += __shfl_xor(num2, 32);
    num3 += __shfl_xor(num3, 16); num3 += __shfl_xor(num3, 32);
    const int srcl = lane >> 2;
    float dA = __shfl(den0, srcl), dB = __shfl(den1, srcl);
    float dC = __shfl(den2, srcl), dD = __shfl(den3, srcl);
    float nA = __shfl(num0, srcl), nB = __shfl(num1, srcl);
    float nC = __shfl(num2, srcl), nD = __shfl(num3, srcl);
    const int e = lane & 3;
    float den = (e & 2) ? ((e & 1) ? dD : dC) : ((e & 1) ? dB : dA);
    float num = (e & 2) ? ((e & 1) ? nD : nC) : ((e & 1) ? nB : nA);
    return den > 0.f ? num / den : 0.f;
}

__global__ __launch_bounds__(256) void k_gather0(
    const float* __restrict__ xenc, const short* __restrict__ msgb,
    const int* __restrict__ row_ptr,
    const float* __restrict__ wr, const float* __restrict__ g,
    const float* __restrict__ b, const float* __restrict__ tp,
    float* __restrict__ x1, short* __restrict__ hb)
{
    const int wave = threadIdx.x >> 6, lane = threadIdx.x & 63;
    const int node = blockIdx.x * 4 + wave;
    if (node >= NN) return;
    const float* xr = xenc + (size_t)node * 64;
    float root = 0.f;
    #pragma unroll
    for (int k = 0; k < 64; ++k) root = fmaf(xr[k], wr[k * 64 + lane], root);
    float agg = gather_agg(msgb, row_ptr[node], row_ptr[node + 1], tp[0], lane);
    float v = root + agg;
    size_t idx = (size_t)node * 64 + lane;
    x1[idx] = v;
    float s = v, s2 = v * v;
    #pragma unroll
    for (int off = 32; off; off >>= 1) { s += __shfl_xor(s, off); s2 += __shfl_xor(s2, off); }
    float mu = s * 0.015625f, var = s2 * 0.015625f - mu * mu;
    float r = rsqrtf(var + 1e-5f);
    hb[idx] = f2bf(fmaxf((v - mu) * r * g[lane] + b[lane], 0.f));
}

__global__ __launch_bounds__(256) void k_gather1(
    const float* __restrict__ x1, const short* __restrict__ hb,
    const short* __restrict__ msgb, const int* __restrict__ row_ptr,
    const float* __restrict__ wr, const float* __restrict__ tp,
    float* __restrict__ out)
{
    const int wave = threadIdx.x >> 6, lane = threadIdx.x & 63;
    const int node = blockIdx.x * 4 + wave;
    if (node >= NN) return;
    const short* hr = hb + (size_t)node * 64;
    float root = 0.f;
    #pragma unroll
    for (int k = 0; k < 64; ++k) root = fmaf(bf2f(hr[k]), wr[k * 64 + lane], root);
    float agg = gather_agg(msgb, row_ptr[node], row_ptr[node + 1], tp[0], lane);
    size_t idx = (size_t)node * 64 + lane;
    out[idx] = x1[idx] + root + agg;
}

extern "C" void kernel_launch(void* const* d_in, const int* in_sizes, int n_in,
                              void* d_out, int out_size, void* d_ws, size_t ws_size,
                              hipStream_t stream)
{
    const float* x       = (const float*)d_in[0];
    const int*   eidx    = (const int*)  d_in[1];
    const float* eattr   = (const float*)d_in[2];
    const float* enc_w   = (const float*)d_in[3];
    const float* enc_b   = (const float*)d_in[4];
    const float* enc_g   = (const float*)d_in[5];
    const float* enc_bb  = (const float*)d_in[6];
    const float* eenc_w  = (const float*)d_in[7];
    const float* eenc_b  = (const float*)d_in[8];
    const float* eenc_g  = (const float*)d_in[9];
    const float* eenc_bb = (const float*)d_in[10];
    const float* c0_w1   = (const float*)d_in[11];
    const float* c0_b1   = (const float*)d_in[12];
    const float* c0_w2   = (const float*)d_in[13];
    const float* c0_b2   = (const float*)d_in[14];
    const float* c0_wr   = (const float*)d_in[15];
    const float* c0_t    = (const float*)d_in[16];
    const float* l1_g    = (const float*)d_in[17];
    const float* l1_b    = (const float*)d_in[18];
    const float* l1_eg   = (const float*)d_in[19];
    const float* l1_eb   = (const float*)d_in[20];
    const float* c1_w1   = (const float*)d_in[21];
    const float* c1_b1   = (const float*)d_in[22];
    const float* c1_w2   = (const float*)d_in[23];
    const float* c1_b2   = (const float*)d_in[24];
    const float* c1_wr   = (const float*)d_in[25];
    const float* c1_t    = (const float*)d_in[26];

    const size_t NV = (size_t)NN * 64;
    char* base = (char*)d_ws;
    auto take = [&](size_t bytes) {
        char* p = base;
        base += (bytes + 255) & ~(size_t)255;
        return p;
    };
    float* xenc    = (float*)take(NV * 4);
    float* x1      = (float*)take(NV * 4);
    int*   deg     = (int*)  take(NN * 4);
    int*   row_ptr = (int*)  take((NN + 1) * 4);
    int*   cursor  = (int*)  take(NN * 4);
    int*   psrc    = (int*)  take((size_t)NE * 4);
    int*   pdst    = (int*)  take((size_t)NE * 4);
    int*   peid    = (int*)  take((size_t)NE * 4);
    short* xb      = (short*)take(NV * 2);
    short* hb      = (short*)take(NV * 2);
    short* w1p0    = (short*)take(24576 * 2);
    short* w1p1    = (short*)take(24576 * 2);
    short* w2p0    = (short*)take(8192 * 2);
    short* w2p1    = (short*)take(8192 * 2);
    short* pbenc   = (short*)take(2048 * 2);
    float* b1e0    = (float*)take(128 * 4);
    float* b1e1    = (float*)take(128 * 4);
    short* msgb    = (short*)take((size_t)NE * 64 * 2);
    float* out     = (float*)d_out;

    hipMemsetAsync(deg, 0, NN * sizeof(int), stream);

    k_pre<<<NN / 4, 256, 0, stream>>>(
        x, eidx, enc_w, enc_b, enc_g, enc_bb,
        c0_w1, c0_w2, c1_w1, c1_w2, eenc_w,
        eenc_g, eenc_bb, l1_eg, l1_eb, c0_b1, c1_b1,
        xenc, xb, deg, w1p0, w2p0, w1p1, w2p1, pbenc, b1e0, b1e1);
    k_scan   <<<1, 1024, 0, stream>>>(deg, row_ptr, cursor);
    k_scatter<<<NE / 256, 256, 0, stream>>>(eidx, cursor, psrc, pdst, peid);

    k_conv_mfma<0><<<1024, 256, 0, stream>>>(
        xb, psrc, pdst, peid, eattr, pbenc, eenc_b,
        w1p0, b1e0, w2p0, c0_b2, msgb);

    k_gather0<<<NN / 4, 256, 0, stream>>>(
        xenc, msgb, row_ptr, c0_wr, l1_g, l1_b, c0_t, x1, hb);

    k_conv_mfma<1><<<1024, 256, 0, stream>>>(
        hb, psrc, pdst, nullptr, nullptr, nullptr, nullptr,
        w1p1, b1e1, w2p1, c1_b2, msgb);

    k_gather1<<<NN / 4, 256, 0, stream>>>(
        x1, hb, msgb, row_ptr, c1_wr, c1_t, out);
}

// Round 9
// 894.356 us; speedup vs baseline: 1.0249x; 1.0249x over previous
//
#include <hip/hip_runtime.h>

#define NN 20000
#define NE 640000
#define NTILES (NE / 64)
#define XSTR 72    // x_lds / a_lds row stride (shorts): 16B-aligned rows
#define HSTR 136   // h_lds row stride (shorts), cols XOR-swizzled by (m&8)

typedef float f32x4 __attribute__((ext_vector_type(4)));
typedef short short8 __attribute__((ext_vector_type(8)));
union S8I4 { int4 i; short8 s; };

#define MFMA(a, b, c) __builtin_amdgcn_mfma_f32_16x16x32_bf16((a), (b), (c), 0, 0, 0)

__device__ __forceinline__ short f2bf(float f) {
    unsigned u = __float_as_uint(f);
    u = (u + 0x7FFFu + ((u >> 16) & 1u)) >> 16;   // RNE
    return (short)u;
}
__device__ __forceinline__ float bf2f(short s) {
    return __uint_as_float(((unsigned)(unsigned short)s) << 16);
}

// ---------------- fused prologue: prep_w + node_enc + degree ----------------
__global__ __launch_bounds__(256) void k_pre(
    const float* __restrict__ x, const int* __restrict__ eidx,
    const float* __restrict__ enc_w, const float* __restrict__ enc_b,
    const float* __restrict__ enc_g, const float* __restrict__ enc_bb,
    const float* __restrict__ w1a, const float* __restrict__ w2a,
    const float* __restrict__ w1b, const float* __restrict__ w2b,
    const float* __restrict__ eencw,
    const float* __restrict__ g0, const float* __restrict__ be0,
    const float* __restrict__ g1, const float* __restrict__ be1,
    const float* __restrict__ b1a, const float* __restrict__ b1b,
    float* __restrict__ xenc, short* __restrict__ xb, int* __restrict__ deg,
    short* __restrict__ p1a, short* __restrict__ p2a,
    short* __restrict__ p1b, short* __restrict__ p2b,
    short* __restrict__ pbenc, float* __restrict__ b1ea, float* __restrict__ b1eb)
{
    const int bid = blockIdx.x, tid = threadIdx.x;
    // ---- node encoder ----
    {
        int node = bid * 4 + (tid >> 6);
        int lane = tid & 63;
        if (node < NN) {
            const float* xr = x + (size_t)node * 96;
            float acc = enc_b[lane];
            #pragma unroll
            for (int k = 0; k < 96; ++k) acc = fmaf(xr[k], enc_w[k * 64 + lane], acc);
            float s = acc, s2 = acc * acc;
            #pragma unroll
            for (int off = 32; off; off >>= 1) { s += __shfl_xor(s, off); s2 += __shfl_xor(s2, off); }
            float mu = s * 0.015625f, var = s2 * 0.015625f - mu * mu;
            float r = rsqrtf(var + 1e-5f);
            float v = (acc - mu) * r * enc_g[lane] + enc_bb[lane];
            size_t idx = (size_t)node * 64 + lane;
            xenc[idx] = v;
            xb[idx] = f2bf(v);
        }
    }
    // ---- degree ----
    if (bid < 2500) {
        int e = bid * 256 + tid;
        atomicAdd(&deg[eidx[NE + e]], 1);
    }
    // ---- weight pre-pack ----
    if (bid < 96) {
        int idx = bid * 256 + tid;
        {
            int f = idx >> 9, l = (idx >> 3) & 63, j = idx & 7;
            int kt = f >> 3, nt = f & 7;
            int k = kt * 32 + ((l >> 4) << 3) + j;
            int n = (nt << 4) + (l & 15);
            float sa = (k >= 128) ? g0[k - 128] : 1.f;
            float sb = (k >= 128) ? g1[k - 128] : 1.f;
            p1a[idx] = f2bf(sa * w1a[k * 128 + n]);
            p1b[idx] = f2bf(sb * w1b[k * 128 + n]);
        }
        if (idx < 8192) {
            int f = idx >> 9, l = (idx >> 3) & 63, j = idx & 7;
            int kt = f >> 2, nt = f & 3;
            int k = kt * 32 + ((l >> 4) << 3) + j;
            int n = (nt << 4) + (l & 15);
            p2a[idx] = f2bf(w2a[k * 64 + n]);
            p2b[idx] = f2bf(w2b[k * 64 + n]);
        }
        if (idx < 2048) {   // encoder B: K padded 16->32
            int f = idx >> 9, l = (idx >> 3) & 63, j = idx & 7;
            int k = ((l >> 4) << 3) + j;
            int n = (f << 4) + (l & 15);
            pbenc[idx] = (k < 16) ? f2bf(eencw[k * 64 + n]) : (short)0;
        }
        if (idx < 256) {
            int conv = idx >> 7, j = idx & 127;
            const float* w1  = conv ? w1b : w1a;
            const float* bet = conv ? be1 : be0;
            float s = conv ? b1b[j] : b1a[j];
            for (int k = 0; k < 64; ++k) s = fmaf(bet[k], w1[(128 + k) * 128 + j], s);
            (conv ? b1eb : b1ea)[j] = s;
        }
    }
}

__global__ __launch_bounds__(1024) void k_scan(
    const int* __restrict__ deg, int* __restrict__ row_ptr, int* __restrict__ cursor)
{
    __shared__ int sums[1024];
    const int T = 1024, CHUNK = (NN + 1023) / 1024;
    int tid = threadIdx.x;
    int base = tid * CHUNK;
    int local = 0;
    for (int i = 0; i < CHUNK; ++i) { int idx = base + i; if (idx < NN) local += deg[idx]; }
    sums[tid] = local;
    __syncthreads();
    for (int off = 1; off < T; off <<= 1) {
        int v = (tid >= off) ? sums[tid - off] : 0;
        __syncthreads();
        sums[tid] += v;
        __syncthreads();
    }
    int run = (tid == 0) ? 0 : sums[tid - 1];
    for (int i = 0; i < CHUNK; ++i) {
        int idx = base + i;
        if (idx < NN) { row_ptr[idx] = run; cursor[idx] = run; run += deg[idx]; }
    }
    if (tid == T - 1) row_ptr[NN] = run;
}

__global__ __launch_bounds__(256) void k_scatter(
    const int* __restrict__ eidx, int* __restrict__ cursor,
    int* __restrict__ psrc, int* __restrict__ pdst, int* __restrict__ peid)
{
    int e = blockIdx.x * 256 + threadIdx.x;
    if (e < NE) {
        int s = eidx[e], d = eidx[NE + e];
        int p = atomicAdd(&cursor[d], 1);
        psrc[p] = s; pdst[p] = d; peid[p] = e;
    }
}

// ---------------- MFMA edge conv ----------------
// Register budget note (R8 post-mortem): at __launch_bounds__(256,4) the
// unified VGPR+AGPR cap is 128/wave. Persistent regs are B1 only (12 frags
// = 48 VGPRs); B2/Benc are re-loaded per tile from L2 (KB-scale, hot) to
// avoid the R8 spill (VGPR=64 + 530 MB scratch fetch).
template <int MODE>
__global__ __launch_bounds__(256, 4) void k_conv_mfma(
    const short* __restrict__ xb,
    const int* __restrict__ psrc, const int* __restrict__ pdst,
    const int* __restrict__ peid,                      // MODE0
    const float* __restrict__ eattr,                   // MODE0
    const short* __restrict__ pbenc,                   // MODE0
    const float* __restrict__ encb,                    // MODE0 (eenc_b)
    const short* __restrict__ w1p, const float* __restrict__ b1e,
    const short* __restrict__ w2p, const float* __restrict__ b2,
    short* __restrict__ msgb)
{
    __shared__ short smem[192 * XSTR];     // x: rows 0..127; a: rows 128..191
    __shared__ float2 stats[64];
    short* x_lds = smem;
    short* a_lds = smem + 128 * XSTR;
    short* h_lds = smem;                   // overlay on x region (64*HSTR <= 128*XSTR)
    const int tid  = threadIdx.x;
    const int wave = tid >> 6;
    const int lane = tid & 63;
    const int quad = lane >> 4;
    const int l15  = lane & 15;
    const int qoff = quad * 8;

    // persistent: B1 only (48 VGPRs)
    short8 B1[6][2];
    {
        const int4* p = (const int4*)w1p;
        #pragma unroll
        for (int kt = 0; kt < 6; ++kt)
            #pragma unroll
            for (int nf = 0; nf < 2; ++nf) {
                S8I4 u; u.i = p[(kt * 8 + wave * 2 + nf) * 64 + lane];
                B1[kt][nf] = u.s;
            }
    }
    const float b1v0 = b1e[wave * 32 + l15];
    const float b1v1 = b1e[wave * 32 + 16 + l15];
    const float b2v  = b2[wave * 16 + l15];
    const float encbv = (MODE == 0) ? encb[wave * 16 + l15] : 0.f;

    for (int t = blockIdx.x; t < NTILES; t += gridDim.x) {
        const int ebase = t * 64;
        __syncthreads();   // prev tile's layer2 (h in x region) done before restage

        // ---- stage x_dst (rows 0..63) and x_src (rows 64..127) ----
        #pragma unroll
        for (int it = 0; it < 4; ++it) {
            int item = it * 256 + tid;            // 0..1023
            int row = item >> 3, c = item & 7;
            int slot = ebase + (row & 63);
            int node = (row < 64) ? pdst[slot] : psrc[slot];
            *(int4*)(x_lds + row * XSTR + c * 8) =
                *(const int4*)(xb + (size_t)node * 64 + c * 8);
        }
        // ---- stage ea source into a_lds ----
        if (MODE == 1) {
            // stats folded into staging: 8 consecutive lanes share a row
            #pragma unroll
            for (int it = 0; it < 2; ++it) {
                int item = it * 256 + tid;        // 0..511
                int row = item >> 3, c = item & 7;
                S8I4 u;
                u.i = *(const int4*)(msgb + (size_t)(ebase + row) * 64 + c * 8);
                *(int4*)(a_lds + row * XSTR + c * 8) = u.i;
                float s = 0.f, s2 = 0.f;
                #pragma unroll
                for (int j = 0; j < 8; ++j) {
                    float v = bf2f(u.s[j]);
                    s += v; s2 = fmaf(v, v, s2);
                }
                s  += __shfl_xor(s, 1);  s  += __shfl_xor(s, 2);  s  += __shfl_xor(s, 4);
                s2 += __shfl_xor(s2, 1); s2 += __shfl_xor(s2, 2); s2 += __shfl_xor(s2, 4);
                if ((tid & 7) == 0) stats[row] = make_float2(s, s2);
            }
        } else {
            // fused edge encoder (K-padded MFMA from raw attrs); Benc per tile
            S8I4 be; be.i = ((const int4*)pbenc)[wave * 64 + lane];
            #pragma unroll
            for (int mt = 0; mt < 4; ++mt) {
                int slot = ebase + mt * 16 + l15;
                short8 ae = {0, 0, 0, 0, 0, 0, 0, 0};
                if (quad < 2) {
                    int row = peid[slot];
                    const float* ap = eattr + (size_t)row * 16 + qoff;
                    float4 u0 = *(const float4*)ap;
                    float4 u1 = *(const float4*)(ap + 4);
                    ae[0] = f2bf(u0.x); ae[1] = f2bf(u0.y); ae[2] = f2bf(u0.z); ae[3] = f2bf(u0.w);
                    ae[4] = f2bf(u1.x); ae[5] = f2bf(u1.y); ae[6] = f2bf(u1.z); ae[7] = f2bf(u1.w);
                }
                f32x4 ac = {encbv, encbv, encbv, encbv};
                ac = MFMA(ae, be.s, ac);
                #pragma unroll
                for (int r = 0; r < 4; ++r)
                    a_lds[(mt * 16 + quad * 4 + r) * XSTR + wave * 16 + l15] = f2bf(ac[r]);
            }
        }
        __syncthreads();

        if (MODE == 0) {
            // read-only stats pass: 4 consecutive lanes per row
            int m = tid >> 2, q = tid & 3;
            const short* rp = a_lds + m * XSTR + q * 16;
            S8I4 u0, u1;
            u0.i = *(const int4*)rp;
            u1.i = *(const int4*)(rp + 8);
            float s = 0.f, s2 = 0.f;
            #pragma unroll
            for (int j = 0; j < 8; ++j) {
                float v0 = bf2f(u0.s[j]), v1 = bf2f(u1.s[j]);
                s += v0 + v1;
                s2 = fmaf(v0, v0, fmaf(v1, v1, s2));
            }
            s  += __shfl_xor(s, 1);  s  += __shfl_xor(s, 2);
            s2 += __shfl_xor(s2, 1); s2 += __shfl_xor(s2, 2);
            if (q == 0) stats[m] = make_float2(s, s2);
            __syncthreads();
        }

        // ---- layer 1 (reader-side LN on ea fragments) ----
        f32x4 acc[4][2];
        #pragma unroll
        for (int mt = 0; mt < 4; ++mt) {
            acc[mt][0] = (f32x4){b1v0, b1v0, b1v0, b1v0};
            acc[mt][1] = (f32x4){b1v1, b1v1, b1v1, b1v1};
        }
        #pragma unroll
        for (int mt = 0; mt < 4; ++mt) {
            const short* xr = x_lds + (mt * 16 + l15) * XSTR;
            const short* sr = xr + 64 * XSTR;
            const short* ar = a_lds + (mt * 16 + l15) * XSTR;
            float2 sv = stats[mt * 16 + l15];
            float mu = sv.x * 0.015625f, var = sv.y * 0.015625f - mu * mu;
            float rs = rsqrtf(var + 1e-5f);
            float nb = -mu * rs;
            S8I4 a0, a1, a2, a3, r4, r5;
            a0.i = *(const int4*)(xr + qoff);
            a1.i = *(const int4*)(xr + 32 + qoff);
            a2.i = *(const int4*)(sr + qoff);
            a3.i = *(const int4*)(sr + 32 + qoff);
            r4.i = *(const int4*)(ar + qoff);
            r5.i = *(const int4*)(ar + 32 + qoff);
            short8 a4, a5;
            #pragma unroll
            for (int j = 0; j < 8; ++j) {
                a4[j] = f2bf(fmaf(bf2f(r4.s[j]), rs, nb));
                a5[j] = f2bf(fmaf(bf2f(r5.s[j]), rs, nb));
            }
            acc[mt][0] = MFMA(a0.s, B1[0][0], acc[mt][0]);
            acc[mt][1] = MFMA(a0.s, B1[0][1], acc[mt][1]);
            acc[mt][0] = MFMA(a1.s, B1[1][0], acc[mt][0]);
            acc[mt][1] = MFMA(a1.s, B1[1][1], acc[mt][1]);
            acc[mt][0] = MFMA(a2.s, B1[2][0], acc[mt][0]);
            acc[mt][1] = MFMA(a2.s, B1[2][1], acc[mt][1]);
            acc[mt][0] = MFMA(a3.s, B1[3][0], acc[mt][0]);
            acc[mt][1] = MFMA(a3.s, B1[3][1], acc[mt][1]);
            acc[mt][0] = MFMA(a4, B1[4][0], acc[mt][0]);
            acc[mt][1] = MFMA(a4, B1[4][1], acc[mt][1]);
            acc[mt][0] = MFMA(a5, B1[5][0], acc[mt][0]);
            acc[mt][1] = MFMA(a5, B1[5][1], acc[mt][1]);
        }
        __syncthreads();   // all x/a reads done before h overwrites x region

        // ---- relu -> h_lds (overlaid on x region) ----
        #pragma unroll
        for (int mt = 0; mt < 4; ++mt)
            #pragma unroll
            for (int nf = 0; nf < 2; ++nf) {
                int n = wave * 32 + nf * 16 + l15;
                #pragma unroll
                for (int r = 0; r < 4; ++r) {
                    int m = mt * 16 + quad * 4 + r;
                    h_lds[m * HSTR + (n ^ (m & 8))] = f2bf(fmaxf(acc[mt][nf][r], 0.f));
                }
            }
        __syncthreads();

        // ---- layer 2 (B2 loaded per tile from L2 — not persistent) ----
        S8I4 b2f[4];
        #pragma unroll
        for (int kt = 0; kt < 4; ++kt)
            b2f[kt].i = ((const int4*)w2p)[(kt * 4 + wave) * 64 + lane];
        f32x4 acc2[4];
        #pragma unroll
        for (int mt = 0; mt < 4; ++mt) acc2[mt] = (f32x4){b2v, b2v, b2v, b2v};
        #pragma unroll
        for (int mt = 0; mt < 4; ++mt) {
            int m = mt * 16 + l15;
            const short* hr = h_lds + m * HSTR;
            int sw = m & 8;
            #pragma unroll
            for (int kt = 0; kt < 4; ++kt) {
                S8I4 u; u.i = *(const int4*)(hr + ((kt * 32 + qoff) ^ sw));
                acc2[mt] = MFMA(u.s, b2f[kt].s, acc2[mt]);
            }
        }
        #pragma unroll
        for (int mt = 0; mt < 4; ++mt) {
            int n = wave * 16 + l15;
            #pragma unroll
            for (int r = 0; r < 4; ++r) {
                int m = mt * 16 + quad * 4 + r;
                msgb[(size_t)(ebase + m) * 64 + n] = f2bf(acc2[mt][r]);
            }
        }
    }
}

// ---------------- gathers: 4 edges in flight, shuffle-only redistribute ------
__device__ __forceinline__ float gather_agg(
    const short* __restrict__ msgb, int beg, int end, float t, int lane)
{
    const int cl = lane & 15, gq = lane >> 4;
    float den0 = 0.f, den1 = 0.f, den2 = 0.f, den3 = 0.f;
    float num0 = 0.f, num1 = 0.f, num2 = 0.f, num3 = 0.f;
    for (int i = beg + gq; i < end; i += 4) {
        int2 u = *(const int2*)(msgb + (size_t)i * 64 + cl * 4);
        float m0 = bf2f((short)(u.x & 0xffff));
        float m1 = bf2f((short)(u.x >> 16));
        float m2 = bf2f((short)(u.y & 0xffff));
        float m3 = bf2f((short)(u.y >> 16));
        float e0 = __expf(m0 * t), e1 = __expf(m1 * t);
        float e2 = __expf(m2 * t), e3 = __expf(m3 * t);
        den0 += e0; num0 = fmaf(m0, e0, num0);
        den1 += e1; num1 = fmaf(m1, e1, num1);
        den2 += e2; num2 = fmaf(m2, e2, num2);
        den3 += e3; num3 = fmaf(m3, e3, num3);
    }
    den0 += __shfl_xor(den0, 16); den0 += __shfl_xor(den0, 32);
    den1 += __shfl_xor(den1, 16); den1 += __shfl_xor(den1, 32);
    den2 += __shfl_xor(den2, 16); den2 += __shfl_xor(den2, 32);
    den3 += __shfl_xor(den3, 16); den3 += __shfl_xor(den3, 32);
    num0 += __shfl_xor(num0, 16); num0 += __shfl_xor(num0, 32);
    num1 += __shfl_xor(num1, 16); num1 += __shfl_xor(num1, 32);
    num2 += __shfl_xor(num2, 16); num2 += __shfl_xor(num2, 32);
    num3 += __shfl_xor(num3, 16); num3 += __shfl_xor(num3, 32);
    const int srcl = lane >> 2;
    float dA = __shfl(den0, srcl), dB = __shfl(den1, srcl);
    float dC = __shfl(den2, srcl), dD = __shfl(den3, srcl);
    float nA = __shfl(num0, srcl), nB = __shfl(num1, srcl);
    float nC = __shfl(num2, srcl), nD = __shfl(num3, srcl);
    const int e = lane & 3;
    float den = (e & 2) ? ((e & 1) ? dD : dC) : ((e & 1) ? dB : dA);
    float num = (e & 2) ? ((e & 1) ? nD : nC) : ((e & 1) ? nB : nA);
    return den > 0.f ? num / den : 0.f;
}

__global__ __launch_bounds__(256) void k_gather0(
    const float* __restrict__ xenc, const short* __restrict__ msgb,
    const int* __restrict__ row_ptr,
    const float* __restrict__ wr, const float* __restrict__ g,
    const float* __restrict__ b, const float* __restrict__ tp,
    float* __restrict__ x1, short* __restrict__ hb)
{
    const int wave = threadIdx.x >> 6, lane = threadIdx.x & 63;
    const int node = blockIdx.x * 4 + wave;
    if (node >= NN) return;
    const float* xr = xenc + (size_t)node * 64;
    float root = 0.f;
    #pragma unroll
    for (int k = 0; k < 64; ++k) root = fmaf(xr[k], wr[k * 64 + lane], root);
    float agg = gather_agg(msgb, row_ptr[node], row_ptr[node + 1], tp[0], lane);
    float v = root + agg;
    size_t idx = (size_t)node * 64 + lane;
    x1[idx] = v;
    float s = v, s2 = v * v;
    #pragma unroll
    for (int off = 32; off; off >>= 1) { s += __shfl_xor(s, off); s2 += __shfl_xor(s2, off); }
    float mu = s * 0.015625f, var = s2 * 0.015625f - mu * mu;
    float r = rsqrtf(var + 1e-5f);
    hb[idx] = f2bf(fmaxf((v - mu) * r * g[lane] + b[lane], 0.f));
}

__global__ __launch_bounds__(256) void k_gather1(
    const float* __restrict__ x1, const short* __restrict__ hb,
    const short* __restrict__ msgb, const int* __restrict__ row_ptr,
    const float* __restrict__ wr, const float* __restrict__ tp,
    float* __restrict__ out)
{
    const int wave = threadIdx.x >> 6, lane = threadIdx.x & 63;
    const int node = blockIdx.x * 4 + wave;
    if (node >= NN) return;
    const short* hr = hb + (size_t)node * 64;
    float root = 0.f;
    #pragma unroll
    for (int k = 0; k < 64; ++k) root = fmaf(bf2f(hr[k]), wr[k * 64 + lane], root);
    float agg = gather_agg(msgb, row_ptr[node], row_ptr[node + 1], tp[0], lane);
    size_t idx = (size_t)node * 64 + lane;
    out[idx] = x1[idx] + root + agg;
}

extern "C" void kernel_launch(void* const* d_in, const int* in_sizes, int n_in,
                              void* d_out, int out_size, void* d_ws, size_t ws_size,
                              hipStream_t stream)
{
    const float* x       = (const float*)d_in[0];
    const int*   eidx    = (const int*)  d_in[1];
    const float* eattr   = (const float*)d_in[2];
    const float* enc_w   = (const float*)d_in[3];
    const float* enc_b   = (const float*)d_in[4];
    const float* enc_g   = (const float*)d_in[5];
    const float* enc_bb  = (const float*)d_in[6];
    const float* eenc_w  = (const float*)d_in[7];
    const float* eenc_b  = (const float*)d_in[8];
    const float* eenc_g  = (const float*)d_in[9];
    const float* eenc_bb = (const float*)d_in[10];
    const float* c0_w1   = (const float*)d_in[11];
    const float* c0_b1   = (const float*)d_in[12];
    const float* c0_w2   = (const float*)d_in[13];
    const float* c0_b2   = (const float*)d_in[14];
    const float* c0_wr   = (const float*)d_in[15];
    const float* c0_t    = (const float*)d_in[16];
    const float* l1_g    = (const float*)d_in[17];
    const float* l1_b    = (const float*)d_in[18];
    const float* l1_eg   = (const float*)d_in[19];
    const float* l1_eb   = (const float*)d_in[20];
    const float* c1_w1   = (const float*)d_in[21];
    const float* c1_b1   = (const float*)d_in[22];
    const float* c1_w2   = (const float*)d_in[23];
    const float* c1_b2   = (const float*)d_in[24];
    const float* c1_wr   = (const float*)d_in[25];
    const float* c1_t    = (const float*)d_in[26];

    const size_t NV = (size_t)NN * 64;
    char* base = (char*)d_ws;
    auto take = [&](size_t bytes) {
        char* p = base;
        base += (bytes + 255) & ~(size_t)255;
        return p;
    };
    float* xenc    = (float*)take(NV * 4);
    float* x1      = (float*)take(NV * 4);
    int*   deg     = (int*)  take(NN * 4);
    int*   row_ptr = (int*)  take((NN + 1) * 4);
    int*   cursor  = (int*)  take(NN * 4);
    int*   psrc    = (int*)  take((size_t)NE * 4);
    int*   pdst    = (int*)  take((size_t)NE * 4);
    int*   peid    = (int*)  take((size_t)NE * 4);
    short* xb      = (short*)take(NV * 2);
    short* hb      = (short*)take(NV * 2);
    short* w1p0    = (short*)take(24576 * 2);
    short* w1p1    = (short*)take(24576 * 2);
    short* w2p0    = (short*)take(8192 * 2);
    short* w2p1    = (short*)take(8192 * 2);
    short* pbenc   = (short*)take(2048 * 2);
    float* b1e0    = (float*)take(128 * 4);
    float* b1e1    = (float*)take(128 * 4);
    short* msgb    = (short*)take((size_t)NE * 64 * 2);
    float* out     = (float*)d_out;

    hipMemsetAsync(deg, 0, NN * sizeof(int), stream);

    k_pre<<<NN / 4, 256, 0, stream>>>(
        x, eidx, enc_w, enc_b, enc_g, enc_bb,
        c0_w1, c0_w2, c1_w1, c1_w2, eenc_w,
        eenc_g, eenc_bb, l1_eg, l1_eb, c0_b1, c1_b1,
        xenc, xb, deg, w1p0, w2p0, w1p1, w2p1, pbenc, b1e0, b1e1);
    k_scan   <<<1, 1024, 0, stream>>>(deg, row_ptr, cursor);
    k_scatter<<<NE / 256, 256, 0, stream>>>(eidx, cursor, psrc, pdst, peid);

    k_conv_mfma<0><<<1024, 256, 0, stream>>>(
        xb, psrc, pdst, peid, eattr, pbenc, eenc_b,
        w1p0, b1e0, w2p0, c0_b2, msgb);

    k_gather0<<<NN / 4, 256, 0, stream>>>(
        xenc, msgb, row_ptr, c0_wr, l1_g, l1_b, c0_t, x1, hb);

    k_conv_mfma<1><<<1024, 256, 0, stream>>>(
        hb, psrc, pdst, nullptr, nullptr, nullptr, nullptr,
        w1p1, b1e1, w2p1, c1_b2, msgb);

    k_gather1<<<NN / 4, 256, 0, stream>>>(
        x1, hb, msgb, row_ptr, c1_wr, c1_t, out);
}

// Round 10
// 704.711 us; speedup vs baseline: 1.3007x; 1.2691x over previous
//
#include <hip/hip_runtime.h>

#define NN 20000
#define NE 640000
#define NTILES (NE / 64)
#define XSTR 72    // x_lds / a_lds row stride (shorts): 16B-aligned rows
#define HSTR 136   // h_lds row stride (shorts), cols XOR-swizzled by (m&8)

typedef float f32x4 __attribute__((ext_vector_type(4)));
typedef short short8 __attribute__((ext_vector_type(8)));
union S8I4 { int4 i; short8 s; };

#define MFMA(a, b, c) __builtin_amdgcn_mfma_f32_16x16x32_bf16((a), (b), (c), 0, 0, 0)

__device__ __forceinline__ short f2bf(float f) {
    unsigned u = __float_as_uint(f);
    u = (u + 0x7FFFu + ((u >> 16) & 1u)) >> 16;   // RNE
    return (short)u;
}
__device__ __forceinline__ float bf2f(short s) {
    return __uint_as_float(((unsigned)(unsigned short)s) << 16);
}

// ---------------- fused prologue: prep_w + node_enc + degree ----------------
__global__ __launch_bounds__(256) void k_pre(
    const float* __restrict__ x, const int* __restrict__ eidx,
    const float* __restrict__ enc_w, const float* __restrict__ enc_b,
    const float* __restrict__ enc_g, const float* __restrict__ enc_bb,
    const float* __restrict__ w1a, const float* __restrict__ w2a,
    const float* __restrict__ w1b, const float* __restrict__ w2b,
    const float* __restrict__ eencw,
    const float* __restrict__ g0, const float* __restrict__ be0,
    const float* __restrict__ g1, const float* __restrict__ be1,
    const float* __restrict__ b1a, const float* __restrict__ b1b,
    float* __restrict__ xenc, short* __restrict__ xb, int* __restrict__ deg,
    short* __restrict__ p1a, short* __restrict__ p2a,
    short* __restrict__ p1b, short* __restrict__ p2b,
    short* __restrict__ pbenc, float* __restrict__ b1ea, float* __restrict__ b1eb)
{
    const int bid = blockIdx.x, tid = threadIdx.x;
    // ---- node encoder ----
    {
        int node = bid * 4 + (tid >> 6);
        int lane = tid & 63;
        if (node < NN) {
            const float* xr = x + (size_t)node * 96;
            float acc = enc_b[lane];
            #pragma unroll
            for (int k = 0; k < 96; ++k) acc = fmaf(xr[k], enc_w[k * 64 + lane], acc);
            float s = acc, s2 = acc * acc;
            #pragma unroll
            for (int off = 32; off; off >>= 1) { s += __shfl_xor(s, off); s2 += __shfl_xor(s2, off); }
            float mu = s * 0.015625f, var = s2 * 0.015625f - mu * mu;
            float r = rsqrtf(var + 1e-5f);
            float v = (acc - mu) * r * enc_g[lane] + enc_bb[lane];
            size_t idx = (size_t)node * 64 + lane;
            xenc[idx] = v;
            xb[idx] = f2bf(v);
        }
    }
    // ---- degree ----
    if (bid < 2500) {
        int e = bid * 256 + tid;
        atomicAdd(&deg[eidx[NE + e]], 1);
    }
    // ---- weight pre-pack ----
    if (bid < 96) {
        int idx = bid * 256 + tid;
        {
            int f = idx >> 9, l = (idx >> 3) & 63, j = idx & 7;
            int kt = f >> 3, nt = f & 7;
            int k = kt * 32 + ((l >> 4) << 3) + j;
            int n = (nt << 4) + (l & 15);
            float sa = (k >= 128) ? g0[k - 128] : 1.f;
            float sb = (k >= 128) ? g1[k - 128] : 1.f;
            p1a[idx] = f2bf(sa * w1a[k * 128 + n]);
            p1b[idx] = f2bf(sb * w1b[k * 128 + n]);
        }
        if (idx < 8192) {
            int f = idx >> 9, l = (idx >> 3) & 63, j = idx & 7;
            int kt = f >> 2, nt = f & 3;
            int k = kt * 32 + ((l >> 4) << 3) + j;
            int n = (nt << 4) + (l & 15);
            p2a[idx] = f2bf(w2a[k * 64 + n]);
            p2b[idx] = f2bf(w2b[k * 64 + n]);
        }
        if (idx < 2048) {   // encoder B: K padded 16->32
            int f = idx >> 9, l = (idx >> 3) & 63, j = idx & 7;
            int k = ((l >> 4) << 3) + j;
            int n = (f << 4) + (l & 15);
            pbenc[idx] = (k < 16) ? f2bf(eencw[k * 64 + n]) : (short)0;
        }
        if (idx < 256) {
            int conv = idx >> 7, j = idx & 127;
            const float* w1  = conv ? w1b : w1a;
            const float* bet = conv ? be1 : be0;
            float s = conv ? b1b[j] : b1a[j];
            for (int k = 0; k < 64; ++k) s = fmaf(bet[k], w1[(128 + k) * 128 + j], s);
            (conv ? b1eb : b1ea)[j] = s;
        }
    }
}

__global__ __launch_bounds__(1024) void k_scan(
    const int* __restrict__ deg, int* __restrict__ row_ptr, int* __restrict__ cursor)
{
    __shared__ int sums[1024];
    const int T = 1024, CHUNK = (NN + 1023) / 1024;
    int tid = threadIdx.x;
    int base = tid * CHUNK;
    int local = 0;
    for (int i = 0; i < CHUNK; ++i) { int idx = base + i; if (idx < NN) local += deg[idx]; }
    sums[tid] = local;
    __syncthreads();
    for (int off = 1; off < T; off <<= 1) {
        int v = (tid >= off) ? sums[tid - off] : 0;
        __syncthreads();
        sums[tid] += v;
        __syncthreads();
    }
    int run = (tid == 0) ? 0 : sums[tid - 1];
    for (int i = 0; i < CHUNK; ++i) {
        int idx = base + i;
        if (idx < NN) { row_ptr[idx] = run; cursor[idx] = run; run += deg[idx]; }
    }
    if (tid == T - 1) row_ptr[NN] = run;
}

__global__ __launch_bounds__(256) void k_scatter(
    const int* __restrict__ eidx, int* __restrict__ cursor,
    int* __restrict__ psrc, int* __restrict__ pdst, int* __restrict__ peid)
{
    int e = blockIdx.x * 256 + threadIdx.x;
    if (e < NE) {
        int s = eidx[e], d = eidx[NE + e];
        int p = atomicAdd(&cursor[d], 1);
        psrc[p] = s; pdst[p] = d; peid[p] = e;
    }
}

// ---------------- MFMA edge conv ----------------
// Register note (R8/R9 post-mortem): __launch_bounds__(256,4) caps the
// unified file at 128/wave and the allocator splits it 64 arch / 64 acc,
// stranding the persistent B1 frags -> 480 MB/dispatch of scratch reloads.
// (256,3) relaxes the cap to 170; natural usage is ~100-130, and since the
// HW VGPR occupancy step is at 128, actual usage <=128 still yields
// 4 blocks/CU with the 28 KB LDS. Do NOT tighten this bound again.
template <int MODE>
__global__ __launch_bounds__(256, 3) void k_conv_mfma(
    const short* __restrict__ xb,
    const int* __restrict__ psrc, const int* __restrict__ pdst,
    const int* __restrict__ peid,                      // MODE0
    const float* __restrict__ eattr,                   // MODE0
    const short* __restrict__ pbenc,                   // MODE0
    const float* __restrict__ encb,                    // MODE0 (eenc_b)
    const short* __restrict__ w1p, const float* __restrict__ b1e,
    const short* __restrict__ w2p, const float* __restrict__ b2,
    short* __restrict__ msgb)
{
    __shared__ short smem[192 * XSTR];     // x: rows 0..127; a: rows 128..191
    __shared__ float2 stats[64];
    short* x_lds = smem;
    short* a_lds = smem + 128 * XSTR;
    short* h_lds = smem;                   // overlay on x region (64*HSTR <= 128*XSTR)
    const int tid  = threadIdx.x;
    const int wave = tid >> 6;
    const int lane = tid & 63;
    const int quad = lane >> 4;
    const int l15  = lane & 15;
    const int qoff = quad * 8;

    // persistent: B1 only (48 VGPRs)
    short8 B1[6][2];
    {
        const int4* p = (const int4*)w1p;
        #pragma unroll
        for (int kt = 0; kt < 6; ++kt)
            #pragma unroll
            for (int nf = 0; nf < 2; ++nf) {
                S8I4 u; u.i = p[(kt * 8 + wave * 2 + nf) * 64 + lane];
                B1[kt][nf] = u.s;
            }
    }
    const float b1v0 = b1e[wave * 32 + l15];
    const float b1v1 = b1e[wave * 32 + 16 + l15];
    const float b2v  = b2[wave * 16 + l15];
    const float encbv = (MODE == 0) ? encb[wave * 16 + l15] : 0.f;

    for (int t = blockIdx.x; t < NTILES; t += gridDim.x) {
        const int ebase = t * 64;
        __syncthreads();   // prev tile's layer2 (h in x region) done before restage

        // ---- stage x_dst (rows 0..63) and x_src (rows 64..127) ----
        #pragma unroll
        for (int it = 0; it < 4; ++it) {
            int item = it * 256 + tid;            // 0..1023
            int row = item >> 3, c = item & 7;
            int slot = ebase + (row & 63);
            int node = (row < 64) ? pdst[slot] : psrc[slot];
            *(int4*)(x_lds + row * XSTR + c * 8) =
                *(const int4*)(xb + (size_t)node * 64 + c * 8);
        }
        // ---- stage ea source into a_lds ----
        if (MODE == 1) {
            // stats folded into staging: 8 consecutive lanes share a row
            #pragma unroll
            for (int it = 0; it < 2; ++it) {
                int item = it * 256 + tid;        // 0..511
                int row = item >> 3, c = item & 7;
                S8I4 u;
                u.i = *(const int4*)(msgb + (size_t)(ebase + row) * 64 + c * 8);
                *(int4*)(a_lds + row * XSTR + c * 8) = u.i;
                float s = 0.f, s2 = 0.f;
                #pragma unroll
                for (int j = 0; j < 8; ++j) {
                    float v = bf2f(u.s[j]);
                    s += v; s2 = fmaf(v, v, s2);
                }
                s  += __shfl_xor(s, 1);  s  += __shfl_xor(s, 2);  s  += __shfl_xor(s, 4);
                s2 += __shfl_xor(s2, 1); s2 += __shfl_xor(s2, 2); s2 += __shfl_xor(s2, 4);
                if ((tid & 7) == 0) stats[row] = make_float2(s, s2);
            }
        } else {
            // fused edge encoder (K-padded MFMA from raw attrs); Benc per tile
            S8I4 be; be.i = ((const int4*)pbenc)[wave * 64 + lane];
            #pragma unroll
            for (int mt = 0; mt < 4; ++mt) {
                int slot = ebase + mt * 16 + l15;
                short8 ae = {0, 0, 0, 0, 0, 0, 0, 0};
                if (quad < 2) {
                    int row = peid[slot];
                    const float* ap = eattr + (size_t)row * 16 + qoff;
                    float4 u0 = *(const float4*)ap;
                    float4 u1 = *(const float4*)(ap + 4);
                    ae[0] = f2bf(u0.x); ae[1] = f2bf(u0.y); ae[2] = f2bf(u0.z); ae[3] = f2bf(u0.w);
                    ae[4] = f2bf(u1.x); ae[5] = f2bf(u1.y); ae[6] = f2bf(u1.z); ae[7] = f2bf(u1.w);
                }
                f32x4 ac = {encbv, encbv, encbv, encbv};
                ac = MFMA(ae, be.s, ac);
                #pragma unroll
                for (int r = 0; r < 4; ++r)
                    a_lds[(mt * 16 + quad * 4 + r) * XSTR + wave * 16 + l15] = f2bf(ac[r]);
            }
        }
        __syncthreads();

        if (MODE == 0) {
            // read-only stats pass: 4 consecutive lanes per row
            int m = tid >> 2, q = tid & 3;
            const short* rp = a_lds + m * XSTR + q * 16;
            S8I4 u0, u1;
            u0.i = *(const int4*)rp;
            u1.i = *(const int4*)(rp + 8);
            float s = 0.f, s2 = 0.f;
            #pragma unroll
            for (int j = 0; j < 8; ++j) {
                float v0 = bf2f(u0.s[j]), v1 = bf2f(u1.s[j]);
                s += v0 + v1;
                s2 = fmaf(v0, v0, fmaf(v1, v1, s2));
            }
            s  += __shfl_xor(s, 1);  s  += __shfl_xor(s, 2);
            s2 += __shfl_xor(s2, 1); s2 += __shfl_xor(s2, 2);
            if (q == 0) stats[m] = make_float2(s, s2);
            __syncthreads();
        }

        // ---- layer 1 (reader-side LN on ea fragments) ----
        f32x4 acc[4][2];
        #pragma unroll
        for (int mt = 0; mt < 4; ++mt) {
            acc[mt][0] = (f32x4){b1v0, b1v0, b1v0, b1v0};
            acc[mt][1] = (f32x4){b1v1, b1v1, b1v1, b1v1};
        }
        #pragma unroll
        for (int mt = 0; mt < 4; ++mt) {
            const short* xr = x_lds + (mt * 16 + l15) * XSTR;
            const short* sr = xr + 64 * XSTR;
            const short* ar = a_lds + (mt * 16 + l15) * XSTR;
            float2 sv = stats[mt * 16 + l15];
            float mu = sv.x * 0.015625f, var = sv.y * 0.015625f - mu * mu;
            float rs = rsqrtf(var + 1e-5f);
            float nb = -mu * rs;
            S8I4 a0, a1, a2, a3, r4, r5;
            a0.i = *(const int4*)(xr + qoff);
            a1.i = *(const int4*)(xr + 32 + qoff);
            a2.i = *(const int4*)(sr + qoff);
            a3.i = *(const int4*)(sr + 32 + qoff);
            r4.i = *(const int4*)(ar + qoff);
            r5.i = *(const int4*)(ar + 32 + qoff);
            short8 a4, a5;
            #pragma unroll
            for (int j = 0; j < 8; ++j) {
                a4[j] = f2bf(fmaf(bf2f(r4.s[j]), rs, nb));
                a5[j] = f2bf(fmaf(bf2f(r5.s[j]), rs, nb));
            }
            acc[mt][0] = MFMA(a0.s, B1[0][0], acc[mt][0]);
            acc[mt][1] = MFMA(a0.s, B1[0][1], acc[mt][1]);
            acc[mt][0] = MFMA(a1.s, B1[1][0], acc[mt][0]);
            acc[mt][1] = MFMA(a1.s, B1[1][1], acc[mt][1]);
            acc[mt][0] = MFMA(a2.s, B1[2][0], acc[mt][0]);
            acc[mt][1] = MFMA(a2.s, B1[2][1], acc[mt][1]);
            acc[mt][0] = MFMA(a3.s, B1[3][0], acc[mt][0]);
            acc[mt][1] = MFMA(a3.s, B1[3][1], acc[mt][1]);
            acc[mt][0] = MFMA(a4, B1[4][0], acc[mt][0]);
            acc[mt][1] = MFMA(a4, B1[4][1], acc[mt][1]);
            acc[mt][0] = MFMA(a5, B1[5][0], acc[mt][0]);
            acc[mt][1] = MFMA(a5, B1[5][1], acc[mt][1]);
        }
        __syncthreads();   // all x/a reads done before h overwrites x region

        // ---- relu -> h_lds (overlaid on x region) ----
        #pragma unroll
        for (int mt = 0; mt < 4; ++mt)
            #pragma unroll
            for (int nf = 0; nf < 2; ++nf) {
                int n = wave * 32 + nf * 16 + l15;
                #pragma unroll
                for (int r = 0; r < 4; ++r) {
                    int m = mt * 16 + quad * 4 + r;
                    h_lds[m * HSTR + (n ^ (m & 8))] = f2bf(fmaxf(acc[mt][nf][r], 0.f));
                }
            }
        __syncthreads();

        // ---- layer 2 (B2 loaded per tile from L2 — not persistent) ----
        S8I4 b2f[4];
        #pragma unroll
        for (int kt = 0; kt < 4; ++kt)
            b2f[kt].i = ((const int4*)w2p)[(kt * 4 + wave) * 64 + lane];
        f32x4 acc2[4];
        #pragma unroll
        for (int mt = 0; mt < 4; ++mt) acc2[mt] = (f32x4){b2v, b2v, b2v, b2v};
        #pragma unroll
        for (int mt = 0; mt < 4; ++mt) {
            int m = mt * 16 + l15;
            const short* hr = h_lds + m * HSTR;
            int sw = m & 8;
            #pragma unroll
            for (int kt = 0; kt < 4; ++kt) {
                S8I4 u; u.i = *(const int4*)(hr + ((kt * 32 + qoff) ^ sw));
                acc2[mt] = MFMA(u.s, b2f[kt].s, acc2[mt]);
            }
        }
        #pragma unroll
        for (int mt = 0; mt < 4; ++mt) {
            int n = wave * 16 + l15;
            #pragma unroll
            for (int r = 0; r < 4; ++r) {
                int m = mt * 16 + quad * 4 + r;
                msgb[(size_t)(ebase + m) * 64 + n] = f2bf(acc2[mt][r]);
            }
        }
    }
}

// ---------------- gathers: 4 edges in flight, shuffle-only redistribute ------
__device__ __forceinline__ float gather_agg(
    const short* __restrict__ msgb, int beg, int end, float t, int lane)
{
    const int cl = lane & 15, gq = lane >> 4;
    float den0 = 0.f, den1 = 0.f, den2 = 0.f, den3 = 0.f;
    float num0 = 0.f, num1 = 0.f, num2 = 0.f, num3 = 0.f;
    for (int i = beg + gq; i < end; i += 4) {
        int2 u = *(const int2*)(msgb + (size_t)i * 64 + cl * 4);
        float m0 = bf2f((short)(u.x & 0xffff));
        float m1 = bf2f((short)(u.x >> 16));
        float m2 = bf2f((short)(u.y & 0xffff));
        float m3 = bf2f((short)(u.y >> 16));
        float e0 = __expf(m0 * t), e1 = __expf(m1 * t);
        float e2 = __expf(m2 * t), e3 = __expf(m3 * t);
        den0 += e0; num0 = fmaf(m0, e0, num0);
        den1 += e1; num1 = fmaf(m1, e1, num1);
        den2 += e2; num2 = fmaf(m2, e2, num2);
        den3 += e3; num3 = fmaf(m3, e3, num3);
    }
    den0 += __shfl_xor(den0, 16); den0 += __shfl_xor(den0, 32);
    den1 += __shfl_xor(den1, 16); den1 += __shfl_xor(den1, 32);
    den2 += __shfl_xor(den2, 16); den2 += __shfl_xor(den2, 32);
    den3 += __shfl_xor(den3, 16); den3 += __shfl_xor(den3, 32);
    num0 += __shfl_xor(num0, 16); num0 += __shfl_xor(num0, 32);
    num1 += __shfl_xor(num1, 16); num1 += __shfl_xor(num1, 32);
    num2 += __shfl_xor(num2, 16); num2 += __shfl_xor(num2, 32);
    num3 += __shfl_xor(num3, 16); num3 += __shfl_xor(num3, 32);
    const int srcl = lane >> 2;
    float dA = __shfl(den0, srcl), dB = __shfl(den1, srcl);
    float dC = __shfl(den2, srcl), dD = __shfl(den3, srcl);
    float nA = __shfl(num0, srcl), nB = __shfl(num1, srcl);
    float nC = __shfl(num2, srcl), nD = __shfl(num3, srcl);
    const int e = lane & 3;
    float den = (e & 2) ? ((e & 1) ? dD : dC) : ((e & 1) ? dB : dA);
    float num = (e & 2) ? ((e & 1) ? nD : nC) : ((e & 1) ? nB : nA);
    return den > 0.f ? num / den : 0.f;
}

__global__ __launch_bounds__(256) void k_gather0(
    const float* __restrict__ xenc, const short* __restrict__ msgb,
    const int* __restrict__ row_ptr,
    const float* __restrict__ wr, const float* __restrict__ g,
    const float* __restrict__ b, const float* __restrict__ tp,
    float* __restrict__ x1, short* __restrict__ hb)
{
    const int wave = threadIdx.x >> 6, lane = threadIdx.x & 63;
    const int node = blockIdx.x * 4 + wave;
    if (node >= NN) return;
    const float* xr = xenc + (size_t)node * 64;
    float root = 0.f;
    #pragma unroll
    for (int k = 0; k < 64; ++k) root = fmaf(xr[k], wr[k * 64 + lane], root);
    float agg = gather_agg(msgb, row_ptr[node], row_ptr[node + 1], tp[0], lane);
    float v = root + agg;
    size_t idx = (size_t)node * 64 + lane;
    x1[idx] = v;
    float s = v, s2 = v * v;
    #pragma unroll
    for (int off = 32; off; off >>= 1) { s += __shfl_xor(s, off); s2 += __shfl_xor(s2, off); }
    float mu = s * 0.015625f, var = s2 * 0.015625f - mu * mu;
    float r = rsqrtf(var + 1e-5f);
    hb[idx] = f2bf(fmaxf((v - mu) * r * g[lane] + b[lane], 0.f));
}

__global__ __launch_bounds__(256) void k_gather1(
    const float* __restrict__ x1, const short* __restrict__ hb,
    const short* __restrict__ msgb, const int* __restrict__ row_ptr,
    const float* __restrict__ wr, const float* __restrict__ tp,
    float* __restrict__ out)
{
    const int wave = threadIdx.x >> 6, lane = threadIdx.x & 63;
    const int node = blockIdx.x * 4 + wave;
    if (node >= NN) return;
    const short* hr = hb + (size_t)node * 64;
    float root = 0.f;
    #pragma unroll
    for (int k = 0; k < 64; ++k) root = fmaf(bf2f(hr[k]), wr[k * 64 + lane], root);
    float agg = gather_agg(msgb, row_ptr[node], row_ptr[node + 1], tp[0], lane);
    size_t idx = (size_t)node * 64 + lane;
    out[idx] = x1[idx] + root + agg;
}

extern "C" void kernel_launch(void* const* d_in, const int* in_sizes, int n_in,
                              void* d_out, int out_size, void* d_ws, size_t ws_size,
                              hipStream_t stream)
{
    const float* x       = (const float*)d_in[0];
    const int*   eidx    = (const int*)  d_in[1];
    const float* eattr   = (const float*)d_in[2];
    const float* enc_w   = (const float*)d_in[3];
    const float* enc_b   = (const float*)d_in[4];
    const float* enc_g   = (const float*)d_in[5];
    const float* enc_bb  = (const float*)d_in[6];
    const float* eenc_w  = (const float*)d_in[7];
    const float* eenc_b  = (const float*)d_in[8];
    const float* eenc_g  = (const float*)d_in[9];
    const float* eenc_bb = (const float*)d_in[10];
    const float* c0_w1   = (const float*)d_in[11];
    const float* c0_b1   = (const float*)d_in[12];
    const float* c0_w2   = (const float*)d_in[13];
    const float* c0_b2   = (const float*)d_in[14];
    const float* c0_wr   = (const float*)d_in[15];
    const float* c0_t    = (const float*)d_in[16];
    const float* l1_g    = (const float*)d_in[17];
    const float* l1_b    = (const float*)d_in[18];
    const float* l1_eg   = (const float*)d_in[19];
    const float* l1_eb   = (const float*)d_in[20];
    const float* c1_w1   = (const float*)d_in[21];
    const float* c1_b1   = (const float*)d_in[22];
    const float* c1_w2   = (const float*)d_in[23];
    const float* c1_b2   = (const float*)d_in[24];
    const float* c1_wr   = (const float*)d_in[25];
    const float* c1_t    = (const float*)d_in[26];

    const size_t NV = (size_t)NN * 64;
    char* base = (char*)d_ws;
    auto take = [&](size_t bytes) {
        char* p = base;
        base += (bytes + 255) & ~(size_t)255;
        return p;
    };
    float* xenc    = (float*)take(NV * 4);
    float* x1      = (float*)take(NV * 4);
    int*   deg     = (int*)  take(NN * 4);
    int*   row_ptr = (int*)  take((NN + 1) * 4);
    int*   cursor  = (int*)  take(NN * 4);
    int*   psrc    = (int*)  take((size_t)NE * 4);
    int*   pdst    = (int*)  take((size_t)NE * 4);
    int*   peid    = (int*)  take((size_t)NE * 4);
    short* xb      = (short*)take(NV * 2);
    short* hb      = (short*)take(NV * 2);
    short* w1p0    = (short*)take(24576 * 2);
    short* w1p1    = (short*)take(24576 * 2);
    short* w2p0    = (short*)take(8192 * 2);
    short* w2p1    = (short*)take(8192 * 2);
    short* pbenc   = (short*)take(2048 * 2);
    float* b1e0    = (float*)take(128 * 4);
    float* b1e1    = (float*)take(128 * 4);
    short* msgb    = (short*)take((size_t)NE * 64 * 2);
    float* out     = (float*)d_out;

    hipMemsetAsync(deg, 0, NN * sizeof(int), stream);

    k_pre<<<NN / 4, 256, 0, stream>>>(
        x, eidx, enc_w, enc_b, enc_g, enc_bb,
        c0_w1, c0_w2, c1_w1, c1_w2, eenc_w,
        eenc_g, eenc_bb, l1_eg, l1_eb, c0_b1, c1_b1,
        xenc, xb, deg, w1p0, w2p0, w1p1, w2p1, pbenc, b1e0, b1e1);
    k_scan   <<<1, 1024, 0, stream>>>(deg, row_ptr, cursor);
    k_scatter<<<NE / 256, 256, 0, stream>>>(eidx, cursor, psrc, pdst, peid);

    k_conv_mfma<0><<<1024, 256, 0, stream>>>(
        xb, psrc, pdst, peid, eattr, pbenc, eenc_b,
        w1p0, b1e0, w2p0, c0_b2, msgb);

    k_gather0<<<NN / 4, 256, 0, stream>>>(
        xenc, msgb, row_ptr, c0_wr, l1_g, l1_b, c0_t, x1, hb);

    k_conv_mfma<1><<<1024, 256, 0, stream>>>(
        hb, psrc, pdst, nullptr, nullptr, nullptr, nullptr,
        w1p1, b1e1, w2p1, c1_b2, msgb);

    k_gather1<<<NN / 4, 256, 0, stream>>>(
        x1, hb, msgb, row_ptr, c1_wr, c1_t, out);
}

// Round 11
// 519.533 us; speedup vs baseline: 1.7643x; 1.3564x over previous
//
#include <hip/hip_runtime.h>

#define NN 20000
#define NE 640000
#define NTILES (NE / 64)
#define XSTR 72    // x_lds / a_lds row stride (shorts): 16B-aligned rows
#define HSTR 136   // h_lds row stride (shorts), cols XOR-swizzled by (m&8)

typedef float f32x4 __attribute__((ext_vector_type(4)));
typedef short short8 __attribute__((ext_vector_type(8)));
union S8I4 { int4 i; short8 s; };

#define MFMA(a, b, c) __builtin_amdgcn_mfma_f32_16x16x32_bf16((a), (b), (c), 0, 0, 0)

__device__ __forceinline__ short f2bf(float f) {
    unsigned u = __float_as_uint(f);
    u = (u + 0x7FFFu + ((u >> 16) & 1u)) >> 16;   // RNE
    return (short)u;
}
__device__ __forceinline__ float bf2f(short s) {
    return __uint_as_float(((unsigned)(unsigned short)s) << 16);
}

// ---------------- fused prologue: prep_w + node_enc + degree ----------------
__global__ __launch_bounds__(256) void k_pre(
    const float* __restrict__ x, const int* __restrict__ eidx,
    const float* __restrict__ enc_w, const float* __restrict__ enc_b,
    const float* __restrict__ enc_g, const float* __restrict__ enc_bb,
    const float* __restrict__ w1a, const float* __restrict__ w2a,
    const float* __restrict__ w1b, const float* __restrict__ w2b,
    const float* __restrict__ eencw,
    const float* __restrict__ g0, const float* __restrict__ be0,
    const float* __restrict__ g1, const float* __restrict__ be1,
    const float* __restrict__ b1a, const float* __restrict__ b1b,
    float* __restrict__ xenc, short* __restrict__ xb, int* __restrict__ deg,
    short* __restrict__ p1a, short* __restrict__ p2a,
    short* __restrict__ p1b, short* __restrict__ p2b,
    short* __restrict__ pbenc, float* __restrict__ b1ea, float* __restrict__ b1eb)
{
    const int bid = blockIdx.x, tid = threadIdx.x;
    // ---- node encoder ----
    {
        int node = bid * 4 + (tid >> 6);
        int lane = tid & 63;
        if (node < NN) {
            const float* xr = x + (size_t)node * 96;
            float acc = enc_b[lane];
            #pragma unroll
            for (int k = 0; k < 96; ++k) acc = fmaf(xr[k], enc_w[k * 64 + lane], acc);
            float s = acc, s2 = acc * acc;
            #pragma unroll
            for (int off = 32; off; off >>= 1) { s += __shfl_xor(s, off); s2 += __shfl_xor(s2, off); }
            float mu = s * 0.015625f, var = s2 * 0.015625f - mu * mu;
            float r = rsqrtf(var + 1e-5f);
            float v = (acc - mu) * r * enc_g[lane] + enc_bb[lane];
            size_t idx = (size_t)node * 64 + lane;
            xenc[idx] = v;
            xb[idx] = f2bf(v);
        }
    }
    // ---- degree ----
    if (bid < 2500) {
        int e = bid * 256 + tid;
        atomicAdd(&deg[eidx[NE + e]], 1);
    }
    // ---- weight pre-pack ----
    if (bid < 96) {
        int idx = bid * 256 + tid;
        {
            int f = idx >> 9, l = (idx >> 3) & 63, j = idx & 7;
            int kt = f >> 3, nt = f & 7;
            int k = kt * 32 + ((l >> 4) << 3) + j;
            int n = (nt << 4) + (l & 15);
            float sa = (k >= 128) ? g0[k - 128] : 1.f;
            float sb = (k >= 128) ? g1[k - 128] : 1.f;
            p1a[idx] = f2bf(sa * w1a[k * 128 + n]);
            p1b[idx] = f2bf(sb * w1b[k * 128 + n]);
        }
        if (idx < 8192) {
            int f = idx >> 9, l = (idx >> 3) & 63, j = idx & 7;
            int kt = f >> 2, nt = f & 3;
            int k = kt * 32 + ((l >> 4) << 3) + j;
            int n = (nt << 4) + (l & 15);
            p2a[idx] = f2bf(w2a[k * 64 + n]);
            p2b[idx] = f2bf(w2b[k * 64 + n]);
        }
        if (idx < 2048) {   // encoder B: K padded 16->32
            int f = idx >> 9, l = (idx >> 3) & 63, j = idx & 7;
            int k = ((l >> 4) << 3) + j;
            int n = (f << 4) + (l & 15);
            pbenc[idx] = (k < 16) ? f2bf(eencw[k * 64 + n]) : (short)0;
        }
        if (idx < 256) {
            int conv = idx >> 7, j = idx & 127;
            const float* w1  = conv ? w1b : w1a;
            const float* bet = conv ? be1 : be0;
            float s = conv ? b1b[j] : b1a[j];
            for (int k = 0; k < 64; ++k) s = fmaf(bet[k], w1[(128 + k) * 128 + j], s);
            (conv ? b1eb : b1ea)[j] = s;
        }
    }
}

__global__ __launch_bounds__(1024) void k_scan(
    const int* __restrict__ deg, int* __restrict__ row_ptr, int* __restrict__ cursor)
{
    __shared__ int sums[1024];
    const int T = 1024, CHUNK = (NN + 1023) / 1024;
    int tid = threadIdx.x;
    int base = tid * CHUNK;
    int local = 0;
    for (int i = 0; i < CHUNK; ++i) { int idx = base + i; if (idx < NN) local += deg[idx]; }
    sums[tid] = local;
    __syncthreads();
    for (int off = 1; off < T; off <<= 1) {
        int v = (tid >= off) ? sums[tid - off] : 0;
        __syncthreads();
        sums[tid] += v;
        __syncthreads();
    }
    int run = (tid == 0) ? 0 : sums[tid - 1];
    for (int i = 0; i < CHUNK; ++i) {
        int idx = base + i;
        if (idx < NN) { row_ptr[idx] = run; cursor[idx] = run; run += deg[idx]; }
    }
    if (tid == T - 1) row_ptr[NN] = run;
}

__global__ __launch_bounds__(256) void k_scatter(
    const int* __restrict__ eidx, int* __restrict__ cursor,
    int* __restrict__ psrc, int* __restrict__ pdst, int* __restrict__ peid)
{
    int e = blockIdx.x * 256 + threadIdx.x;
    if (e < NE) {
        int s = eidx[e], d = eidx[NE + e];
        int p = atomicAdd(&cursor[d], 1);
        psrc[p] = s; pdst[p] = d; peid[p] = e;
    }
}

// ---------------- MFMA edge conv (Round-5-verified variant) ----------------
// Measured on MI355X (R5): 130 us/dispatch, VGPR 84 (no spill), FETCH 72 MB,
// occupancy 31% (LDS-limited at 45 KB / 3 blocks/CU). R6-R10 variants
// (h-overlay + reader-side LN, tighter bounds) all spilled the unified
// VGPR/AGPR file -> 2-9x scratch HBM traffic. Keep THIS structure.
template <int MODE>
__global__ __launch_bounds__(256, 3) void k_conv_mfma(
    const short* __restrict__ xb,
    const int* __restrict__ psrc, const int* __restrict__ pdst,
    const int* __restrict__ peid,                      // MODE0
    const float* __restrict__ eattr,                   // MODE0
    const short* __restrict__ pbenc,                   // MODE0
    const float* __restrict__ encb,                    // MODE0 (eenc_b)
    const short* __restrict__ w1p, const float* __restrict__ b1e,
    const short* __restrict__ w2p, const float* __restrict__ b2,
    short* __restrict__ msgb)
{
    __shared__ short x_lds[128 * XSTR];
    __shared__ short a_lds[64 * XSTR];
    __shared__ short h_lds[64 * HSTR];
    const int tid  = threadIdx.x;
    const int wave = tid >> 6;
    const int lane = tid & 63;
    const int quad = lane >> 4;
    const int l15  = lane & 15;
    const int qoff = quad * 8;

    short8 B1[6][2], B2[4], Benc;
    {
        const int4* p = (const int4*)w1p;
        #pragma unroll
        for (int kt = 0; kt < 6; ++kt)
            #pragma unroll
            for (int nf = 0; nf < 2; ++nf) {
                S8I4 u; u.i = p[(kt * 8 + wave * 2 + nf) * 64 + lane];
                B1[kt][nf] = u.s;
            }
        const int4* q = (const int4*)w2p;
        #pragma unroll
        for (int kt = 0; kt < 4; ++kt) { S8I4 u; u.i = q[(kt * 4 + wave) * 64 + lane]; B2[kt] = u.s; }
        if (MODE == 0) { S8I4 u; u.i = ((const int4*)pbenc)[wave * 64 + lane]; Benc = u.s; }
    }
    const float b1v0 = b1e[wave * 32 + l15];
    const float b1v1 = b1e[wave * 32 + 16 + l15];
    const float b2v  = b2[wave * 16 + l15];
    const float encbv = (MODE == 0) ? encb[wave * 16 + l15] : 0.f;

    for (int t = blockIdx.x; t < NTILES; t += gridDim.x) {
        const int ebase = t * 64;
        __syncthreads();   // protect LDS from previous iteration's readers

        // ---- stage x_dst (rows 0..63) and x_src (rows 64..127) ----
        #pragma unroll
        for (int it = 0; it < 4; ++it) {
            int item = it * 256 + tid;            // 0..1023
            int row = item >> 3, c = item & 7;
            int slot = ebase + (row & 63);
            int node = (row < 64) ? pdst[slot] : psrc[slot];
            *(int4*)(x_lds + row * XSTR + c * 8) =
                *(const int4*)(xb + (size_t)node * 64 + c * 8);
        }
        // ---- stage ea source into a_lds ----
        if (MODE == 1) {
            #pragma unroll
            for (int it = 0; it < 2; ++it) {
                int item = it * 256 + tid;        // 0..511
                int row = item >> 3, c = item & 7;
                *(int4*)(a_lds + row * XSTR + c * 8) =
                    *(const int4*)(msgb + (size_t)(ebase + row) * 64 + c * 8);
            }
        } else {
            // fused edge encoder (K-padded MFMA from raw attrs)
            #pragma unroll
            for (int mt = 0; mt < 4; ++mt) {
                int slot = ebase + mt * 16 + l15;
                short8 ae = {0, 0, 0, 0, 0, 0, 0, 0};
                if (quad < 2) {
                    int row = peid[slot];
                    const float* ap = eattr + (size_t)row * 16 + qoff;
                    float4 u0 = *(const float4*)ap;
                    float4 u1 = *(const float4*)(ap + 4);
                    ae[0] = f2bf(u0.x); ae[1] = f2bf(u0.y); ae[2] = f2bf(u0.z); ae[3] = f2bf(u0.w);
                    ae[4] = f2bf(u1.x); ae[5] = f2bf(u1.y); ae[6] = f2bf(u1.z); ae[7] = f2bf(u1.w);
                }
                f32x4 ac = {encbv, encbv, encbv, encbv};
                ac = MFMA(ae, Benc, ac);
                #pragma unroll
                for (int r = 0; r < 4; ++r)
                    a_lds[(mt * 16 + quad * 4 + r) * XSTR + wave * 16 + l15] = f2bf(ac[r]);
            }
        }
        __syncthreads();

        // ---- LN stats + normalize in place: a := (v - mu) * rsqrt(var+eps) ----
        {
            int m = tid >> 2, q = tid & 3;
            short* rp = a_lds + m * XSTR + q * 16;
            S8I4 u0, u1;
            u0.i = *(int4*)rp;
            u1.i = *(int4*)(rp + 8);
            float v[16], s = 0.f, s2 = 0.f;
            #pragma unroll
            for (int j = 0; j < 8; ++j) { v[j] = bf2f(u0.s[j]); v[8 + j] = bf2f(u1.s[j]); }
            #pragma unroll
            for (int j = 0; j < 16; ++j) { s += v[j]; s2 = fmaf(v[j], v[j], s2); }
            s  += __shfl_xor(s, 1);  s  += __shfl_xor(s, 2);
            s2 += __shfl_xor(s2, 1); s2 += __shfl_xor(s2, 2);
            float mu = s * 0.015625f, var = s2 * 0.015625f - mu * mu;
            float rs = rsqrtf(var + 1e-5f);
            S8I4 w0, w1u;
            #pragma unroll
            for (int j = 0; j < 8; ++j) {
                w0.s[j]  = f2bf((v[j] - mu) * rs);
                w1u.s[j] = f2bf((v[8 + j] - mu) * rs);
            }
            *(int4*)rp       = w0.i;
            *(int4*)(rp + 8) = w1u.i;
        }
        __syncthreads();

        // ---- layer 1 ----
        f32x4 acc[4][2];
        #pragma unroll
        for (int mt = 0; mt < 4; ++mt) {
            acc[mt][0] = (f32x4){b1v0, b1v0, b1v0, b1v0};
            acc[mt][1] = (f32x4){b1v1, b1v1, b1v1, b1v1};
        }
        #pragma unroll
        for (int mt = 0; mt < 4; ++mt) {
            const short* xr = x_lds + (mt * 16 + l15) * XSTR;
            const short* sr = xr + 64 * XSTR;
            const short* ar = a_lds + (mt * 16 + l15) * XSTR;
            S8I4 a0, a1, a2, a3, a4, a5;
            a0.i = *(const int4*)(xr + qoff);
            a1.i = *(const int4*)(xr + 32 + qoff);
            a2.i = *(const int4*)(sr + qoff);
            a3.i = *(const int4*)(sr + 32 + qoff);
            a4.i = *(const int4*)(ar + qoff);
            a5.i = *(const int4*)(ar + 32 + qoff);
            acc[mt][0] = MFMA(a0.s, B1[0][0], acc[mt][0]);
            acc[mt][1] = MFMA(a0.s, B1[0][1], acc[mt][1]);
            acc[mt][0] = MFMA(a1.s, B1[1][0], acc[mt][0]);
            acc[mt][1] = MFMA(a1.s, B1[1][1], acc[mt][1]);
            acc[mt][0] = MFMA(a2.s, B1[2][0], acc[mt][0]);
            acc[mt][1] = MFMA(a2.s, B1[2][1], acc[mt][1]);
            acc[mt][0] = MFMA(a3.s, B1[3][0], acc[mt][0]);
            acc[mt][1] = MFMA(a3.s, B1[3][1], acc[mt][1]);
            acc[mt][0] = MFMA(a4.s, B1[4][0], acc[mt][0]);
            acc[mt][1] = MFMA(a4.s, B1[4][1], acc[mt][1]);
            acc[mt][0] = MFMA(a5.s, B1[5][0], acc[mt][0]);
            acc[mt][1] = MFMA(a5.s, B1[5][1], acc[mt][1]);
        }
        __syncthreads();   // a_lds reads done before h writes

        // ---- relu -> h_lds (bf16, XOR-swizzled columns) ----
        #pragma unroll
        for (int mt = 0; mt < 4; ++mt)
            #pragma unroll
            for (int nf = 0; nf < 2; ++nf) {
                int n = wave * 32 + nf * 16 + l15;
                #pragma unroll
                for (int r = 0; r < 4; ++r) {
                    int m = mt * 16 + quad * 4 + r;
                    h_lds[m * HSTR + (n ^ (m & 8))] = f2bf(fmaxf(acc[mt][nf][r], 0.f));
                }
            }
        __syncthreads();

        // ---- layer 2 ----
        f32x4 acc2[4];
        #pragma unroll
        for (int mt = 0; mt < 4; ++mt) acc2[mt] = (f32x4){b2v, b2v, b2v, b2v};
        #pragma unroll
        for (int mt = 0; mt < 4; ++mt) {
            int m = mt * 16 + l15;
            const short* hr = h_lds + m * HSTR;
            int sw = m & 8;
            #pragma unroll
            for (int kt = 0; kt < 4; ++kt) {
                S8I4 u; u.i = *(const int4*)(hr + ((kt * 32 + qoff) ^ sw));
                acc2[mt] = MFMA(u.s, B2[kt], acc2[mt]);
            }
        }
        #pragma unroll
        for (int mt = 0; mt < 4; ++mt) {
            int n = wave * 16 + l15;
            #pragma unroll
            for (int r = 0; r < 4; ++r) {
                int m = mt * 16 + quad * 4 + r;
                msgb[(size_t)(ebase + m) * 64 + n] = f2bf(acc2[mt][r]);
            }
        }
    }
}

// ---------------- gathers: 4 edges in flight, shuffle-only redistribute ------
__device__ __forceinline__ float gather_agg(
    const short* __restrict__ msgb, int beg, int end, float t, int lane)
{
    const int cl = lane & 15, gq = lane >> 4;
    float den0 = 0.f, den1 = 0.f, den2 = 0.f, den3 = 0.f;
    float num0 = 0.f, num1 = 0.f, num2 = 0.f, num3 = 0.f;
    for (int i = beg + gq; i < end; i += 4) {
        int2 u = *(const int2*)(msgb + (size_t)i * 64 + cl * 4);
        float m0 = bf2f((short)(u.x & 0xffff));
        float m1 = bf2f((short)(u.x >> 16));
        float m2 = bf2f((short)(u.y & 0xffff));
        float m3 = bf2f((short)(u.y >> 16));
        float e0 = __expf(m0 * t), e1 = __expf(m1 * t);
        float e2 = __expf(m2 * t), e3 = __expf(m3 * t);
        den0 += e0; num0 = fmaf(m0, e0, num0);
        den1 += e1; num1 = fmaf(m1, e1, num1);
        den2 += e2; num2 = fmaf(m2, e2, num2);
        den3 += e3; num3 = fmaf(m3, e3, num3);
    }
    den0 += __shfl_xor(den0, 16); den0 += __shfl_xor(den0, 32);
    den1 += __shfl_xor(den1, 16); den1 += __shfl_xor(den1, 32);
    den2 += __shfl_xor(den2, 16); den2 += __shfl_xor(den2, 32);
    den3 += __shfl_xor(den3, 16); den3 += __shfl_xor(den3, 32);
    num0 += __shfl_xor(num0, 16); num0 += __shfl_xor(num0, 32);
    num1 += __shfl_xor(num1, 16); num1 += __shfl_xor(num1, 32);
    num2 += __shfl_xor(num2, 16); num2 += __shfl_xor(num2, 32);
    num3 += __shfl_xor(num3, 16); num3 += __shfl_xor(num3, 32);
    const int srcl = lane >> 2;
    float dA = __shfl(den0, srcl), dB = __shfl(den1, srcl);
    float dC = __shfl(den2, srcl), dD = __shfl(den3, srcl);
    float nA = __shfl(num0, srcl), nB = __shfl(num1, srcl);
    float nC = __shfl(num2, srcl), nD = __shfl(num3, srcl);
    const int e = lane & 3;
    float den = (e & 2) ? ((e & 1) ? dD : dC) : ((e & 1) ? dB : dA);
    float num = (e & 2) ? ((e & 1) ? nD : nC) : ((e & 1) ? nB : nA);
    return den > 0.f ? num / den : 0.f;
}

__global__ __launch_bounds__(256) void k_gather0(
    const float* __restrict__ xenc, const short* __restrict__ msgb,
    const int* __restrict__ row_ptr,
    const float* __restrict__ wr, const float* __restrict__ g,
    const float* __restrict__ b, const float* __restrict__ tp,
    float* __restrict__ x1, short* __restrict__ hb)
{
    const int wave = threadIdx.x >> 6, lane = threadIdx.x & 63;
    const int node = blockIdx.x * 4 + wave;
    if (node >= NN) return;
    const float* xr = xenc + (size_t)node * 64;
    float root = 0.f;
    #pragma unroll
    for (int k = 0; k < 64; ++k) root = fmaf(xr[k], wr[k * 64 + lane], root);
    float agg = gather_agg(msgb, row_ptr[node], row_ptr[node + 1], tp[0], lane);
    float v = root + agg;
    size_t idx = (size_t)node * 64 + lane;
    x1[idx] = v;
    float s = v, s2 = v * v;
    #pragma unroll
    for (int off = 32; off; off >>= 1) { s += __shfl_xor(s, off); s2 += __shfl_xor(s2, off); }
    float mu = s * 0.015625f, var = s2 * 0.015625f - mu * mu;
    float r = rsqrtf(var + 1e-5f);
    hb[idx] = f2bf(fmaxf((v - mu) * r * g[lane] + b[lane], 0.f));
}

__global__ __launch_bounds__(256) void k_gather1(
    const float* __restrict__ x1, const short* __restrict__ hb,
    const short* __restrict__ msgb, const int* __restrict__ row_ptr,
    const float* __restrict__ wr, const float* __restrict__ tp,
    float* __restrict__ out)
{
    const int wave = threadIdx.x >> 6, lane = threadIdx.x & 63;
    const int node = blockIdx.x * 4 + wave;
    if (node >= NN) return;
    const short* hr = hb + (size_t)node * 64;
    float root = 0.f;
    #pragma unroll
    for (int k = 0; k < 64; ++k) root = fmaf(bf2f(hr[k]), wr[k * 64 + lane], root);
    float agg = gather_agg(msgb, row_ptr[node], row_ptr[node + 1], tp[0], lane);
    size_t idx = (size_t)node * 64 + lane;
    out[idx] = x1[idx] + root + agg;
}

extern "C" void kernel_launch(void* const* d_in, const int* in_sizes, int n_in,
                              void* d_out, int out_size, void* d_ws, size_t ws_size,
                              hipStream_t stream)
{
    const float* x       = (const float*)d_in[0];
    const int*   eidx    = (const int*)  d_in[1];
    const float* eattr   = (const float*)d_in[2];
    const float* enc_w   = (const float*)d_in[3];
    const float* enc_b   = (const float*)d_in[4];
    const float* enc_g   = (const float*)d_in[5];
    const float* enc_bb  = (const float*)d_in[6];
    const float* eenc_w  = (const float*)d_in[7];
    const float* eenc_b  = (const float*)d_in[8];
    const float* eenc_g  = (const float*)d_in[9];
    const float* eenc_bb = (const float*)d_in[10];
    const float* c0_w1   = (const float*)d_in[11];
    const float* c0_b1   = (const float*)d_in[12];
    const float* c0_w2   = (const float*)d_in[13];
    const float* c0_b2   = (const float*)d_in[14];
    const float* c0_wr   = (const float*)d_in[15];
    const float* c0_t    = (const float*)d_in[16];
    const float* l1_g    = (const float*)d_in[17];
    const float* l1_b    = (const float*)d_in[18];
    const float* l1_eg   = (const float*)d_in[19];
    const float* l1_eb   = (const float*)d_in[20];
    const float* c1_w1   = (const float*)d_in[21];
    const float* c1_b1   = (const float*)d_in[22];
    const float* c1_w2   = (const float*)d_in[23];
    const float* c1_b2   = (const float*)d_in[24];
    const float* c1_wr   = (const float*)d_in[25];
    const float* c1_t    = (const float*)d_in[26];

    const size_t NV = (size_t)NN * 64;
    char* base = (char*)d_ws;
    auto take = [&](size_t bytes) {
        char* p = base;
        base += (bytes + 255) & ~(size_t)255;
        return p;
    };
    float* xenc    = (float*)take(NV * 4);
    float* x1      = (float*)take(NV * 4);
    int*   deg     = (int*)  take(NN * 4);
    int*   row_ptr = (int*)  take((NN + 1) * 4);
    int*   cursor  = (int*)  take(NN * 4);
    int*   psrc    = (int*)  take((size_t)NE * 4);
    int*   pdst    = (int*)  take((size_t)NE * 4);
    int*   peid    = (int*)  take((size_t)NE * 4);
    short* xb      = (short*)take(NV * 2);
    short* hb      = (short*)take(NV * 2);
    short* w1p0    = (short*)take(24576 * 2);
    short* w1p1    = (short*)take(24576 * 2);
    short* w2p0    = (short*)take(8192 * 2);
    short* w2p1    = (short*)take(8192 * 2);
    short* pbenc   = (short*)take(2048 * 2);
    float* b1e0    = (float*)take(128 * 4);
    float* b1e1    = (float*)take(128 * 4);
    short* msgb    = (short*)take((size_t)NE * 64 * 2);
    float* out     = (float*)d_out;

    hipMemsetAsync(deg, 0, NN * sizeof(int), stream);

    k_pre<<<NN / 4, 256, 0, stream>>>(
        x, eidx, enc_w, enc_b, enc_g, enc_bb,
        c0_w1, c0_w2, c1_w1, c1_w2, eenc_w,
        eenc_g, eenc_bb, l1_eg, l1_eb, c0_b1, c1_b1,
        xenc, xb, deg, w1p0, w2p0, w1p1, w2p1, pbenc, b1e0, b1e1);
    k_scan   <<<1, 1024, 0, stream>>>(deg, row_ptr, cursor);
    k_scatter<<<NE / 256, 256, 0, stream>>>(eidx, cursor, psrc, pdst, peid);

    k_conv_mfma<0><<<768, 256, 0, stream>>>(
        xb, psrc, pdst, peid, eattr, pbenc, eenc_b,
        w1p0, b1e0, w2p0, c0_b2, msgb);

    k_gather0<<<NN / 4, 256, 0, stream>>>(
        xenc, msgb, row_ptr, c0_wr, l1_g, l1_b, c0_t, x1, hb);

    k_conv_mfma<1><<<768, 256, 0, stream>>>(
        hb, psrc, pdst, nullptr, nullptr, nullptr, nullptr,
        w1p1, b1e1, w2p1, c1_b2, msgb);

    k_gather1<<<NN / 4, 256, 0, stream>>>(
        x1, hb, msgb, row_ptr, c1_wr, c1_t, out);
}